// Round 2
// baseline (387.464 us; speedup 1.0000x reference)
//
#include <hip/hip_runtime.h>
#include <hip/hip_bf16.h>

typedef __attribute__((ext_vector_type(8))) short short8;
typedef __attribute__((ext_vector_type(4))) short short4v;
typedef __attribute__((ext_vector_type(4))) float f32x4;

#define DEVFN static __device__ __forceinline__

constexpr int D_MODEL = 1024;
constexpr int NH  = 16;
constexpr int DH  = 64;
constexpr int SEQ = 2048;
// softmax computed in exp2 domain: p = exp2(s * SCALE * log2(e) - m)
constexpr float SCALE_LOG2E = 0.125f * 1.44269504088896341f;

DEVFN short bf16s(float f) {
  __hip_bfloat16 h = __float2bfloat16(f);
  short s; __builtin_memcpy(&s, &h, 2);
  return s;
}

DEVFN float fast_exp2(float x) {
#if __has_builtin(__builtin_amdgcn_exp2f)
  return __builtin_amdgcn_exp2f(x);
#else
  return exp2f(x);
#endif
}

// ---------------- GEMM: C = A @ B^T  (torch Linear: x @ W.T) ----------------
// A: [4096][1024] rows (f32 for MODE 0/1, bf16 for MODE 2)
// B: [1024][1024] f32 weights, row j = output feature j  (so B^T form already)
// MODE 0: C -> bf16 [B,H,SEQ,DH]  (per-head Q/K layout)
// MODE 1: C -> bf16 [B,H,DH,SEQ]  (transposed V layout, PV B-operand friendly)
// MODE 2: C -> f32  [4096][1024] + bias
template<int MODE>
__global__ __launch_bounds__(256)
void gemm_bt(const void* __restrict__ Ap, const float* __restrict__ Bp,
             const float* __restrict__ bias, void* __restrict__ Cp)
{
  constexpr int BM = 128, BN = 64, BK = 32;
  __shared__ short As[BM][BK + 8];   // +8 bf16 pad: breaks 8-way bank conflict
  __shared__ short Bs[BN][BK + 8];

  const int tid  = threadIdx.x;
  const int lane = tid & 63;
  const int w    = tid >> 6;      // 0..3
  const int wr   = w >> 1;        // 64-row block of wave
  const int wc   = w & 1;         // 32-col block of wave
  const int m0   = blockIdx.y * BM;
  const int n0   = blockIdx.x * BN;
  const int l15  = lane & 15;
  const int l4   = lane >> 4;

  f32x4 acc[4][2];
  #pragma unroll
  for (int i = 0; i < 4; ++i)
    #pragma unroll
    for (int j = 0; j < 2; ++j) acc[i][j] = f32x4{0.f,0.f,0.f,0.f};

  const int sr = tid >> 3;        // staging: 8 threads/row
  const int sc = (tid & 7) * 4;   // 4 floats each (16B)

  for (int kt = 0; kt < D_MODEL / BK; ++kt) {
    const int k0 = kt * BK;
    if (MODE == 2) {
      const short* Ab = (const short*)Ap;
      const int ar = tid >> 2, ac = (tid & 3) * 8;   // 4 thr/row, 16B each
      #pragma unroll
      for (int p = 0; p < 2; ++p) {
        short8 v = *(const short8*)(Ab + (size_t)(m0 + ar + p*64) * D_MODEL + k0 + ac);
        *(short8*)&As[ar + p*64][ac] = v;
      }
    } else {
      const float* Af = (const float*)Ap;
      #pragma unroll
      for (int p = 0; p < 4; ++p) {
        const float4 v = *(const float4*)(Af + (size_t)(m0 + sr + p*32) * D_MODEL + k0 + sc);
        short4v pk;
        pk[0] = bf16s(v.x); pk[1] = bf16s(v.y); pk[2] = bf16s(v.z); pk[3] = bf16s(v.w);
        *(short4v*)&As[sr + p*32][sc] = pk;
      }
    }
    #pragma unroll
    for (int p = 0; p < 2; ++p) {
      const float4 v = *(const float4*)(Bp + (size_t)(n0 + sr + p*32) * D_MODEL + k0 + sc);
      short4v pk;
      pk[0] = bf16s(v.x); pk[1] = bf16s(v.y); pk[2] = bf16s(v.z); pk[3] = bf16s(v.w);
      *(short4v*)&Bs[sr + p*32][sc] = pk;
    }
    __syncthreads();

    short8 af[4], bf[2];
    #pragma unroll
    for (int fi = 0; fi < 4; ++fi)
      af[fi] = *(const short8*)&As[wr*64 + fi*16 + l15][l4*8];
    #pragma unroll
    for (int fj = 0; fj < 2; ++fj)
      bf[fj] = *(const short8*)&Bs[wc*32 + fj*16 + l15][l4*8];
    #pragma unroll
    for (int fi = 0; fi < 4; ++fi)
      #pragma unroll
      for (int fj = 0; fj < 2; ++fj)
        acc[fi][fj] = __builtin_amdgcn_mfma_f32_16x16x32_bf16(af[fi], bf[fj], acc[fi][fj], 0, 0, 0);
    __syncthreads();
  }

  // C/D layout: col = lane&15, row = (lane>>4)*4 + r   [verified m89/m91]
  #pragma unroll
  for (int fi = 0; fi < 4; ++fi)
    #pragma unroll
    for (int fj = 0; fj < 2; ++fj)
      #pragma unroll
      for (int r = 0; r < 4; ++r) {
        const int m = m0 + wr*64 + fi*16 + l4*4 + r;
        const int j = n0 + wc*32 + fj*16 + l15;
        const float v = acc[fi][fj][r];
        if (MODE == 0) {
          const int b = m >> 11, n = m & (SEQ - 1);
          const int h = j >> 6,  d = j & 63;
          ((__hip_bfloat16*)Cp)[(((size_t)(b*NH + h) * SEQ + n) << 6) + d] = __float2bfloat16(v);
        } else if (MODE == 1) {
          const int b = m >> 11, n = m & (SEQ - 1);
          const int h = j >> 6,  d = j & 63;
          ((__hip_bfloat16*)Cp)[((size_t)(b*NH + h) * DH + d) * SEQ + n] = __float2bfloat16(v);
        } else {
          ((float*)Cp)[(size_t)m * D_MODEL + j] = v + bias[j];
        }
      }
}

// ---------------- Flash attention ----------------
// Qh/Kh: bf16 [B*H][SEQ][64], Vt: bf16 [B*H][64][SEQ]
// AO: bf16 [B][SEQ][1024] (heads re-interleaved for the output projection)
__global__ __launch_bounds__(256)
void attn_fwd(const short* __restrict__ Qh, const short* __restrict__ Kh,
              const short* __restrict__ Vt, __hip_bfloat16* __restrict__ AO)
{
  __shared__ short Ks[64][72];      // K tile  [kv][d],  pad to 72 (2-way max)
  __shared__ short Vs[64][72];      // Vt tile [d][kv]
  __shared__ short Ps[4][32][72];   // per-wave P round-trip (32 q-rows x 64 kv-cols + pad)

  const int tid = threadIdx.x, lane = tid & 63, w = tid >> 6;
  const int l15 = lane & 15, l4 = lane >> 4;
  const int bh = blockIdx.y;            // 0..31
  const int q0 = blockIdx.x * 128;      // Q tile of 128 rows; wave owns 32
  const int b  = bh >> 4, h = bh & 15;
  const size_t base = (size_t)bh * SEQ * DH;

  // Q fragments held in registers for the whole kernel
  short8 qf[2][2];
  #pragma unroll
  for (int fi = 0; fi < 2; ++fi)
    #pragma unroll
    for (int kc = 0; kc < 2; ++kc)
      qf[fi][kc] = *(const short8*)(Qh + base + (size_t)(q0 + w*32 + fi*16 + l15)*DH + kc*32 + l4*8);

  float mm[2][4], ll[2][4];
  f32x4 o[2][4];
  #pragma unroll
  for (int fi = 0; fi < 2; ++fi) {
    #pragma unroll
    for (int r = 0; r < 4; ++r) { mm[fi][r] = -1e30f; ll[fi][r] = 0.f; }
    #pragma unroll
    for (int fj = 0; fj < 4; ++fj) o[fi][fj] = f32x4{0.f,0.f,0.f,0.f};
  }

  const int sr = tid >> 3, sc = (tid & 7) * 8;  // staging: 8 thr/row, 16B each

  for (int kt = 0; kt < SEQ/64; ++kt) {
    #pragma unroll
    for (int p = 0; p < 2; ++p) {
      const int r = sr + p*32;
      *(short8*)&Ks[r][sc] = *(const short8*)(Kh + base + (size_t)(kt*64 + r)*DH + sc);
      *(short8*)&Vs[r][sc] = *(const short8*)(Vt + base + (size_t)r*SEQ + kt*64 + sc);
    }
    __syncthreads();

    // S = Q K^T  (wave: 32 q-rows x 64 kv-cols)
    f32x4 s[2][4];
    #pragma unroll
    for (int fi = 0; fi < 2; ++fi)
      #pragma unroll
      for (int fj = 0; fj < 4; ++fj) s[fi][fj] = f32x4{0.f,0.f,0.f,0.f};
    #pragma unroll
    for (int kc = 0; kc < 2; ++kc) {
      short8 kf[4];
      #pragma unroll
      for (int fj = 0; fj < 4; ++fj)
        kf[fj] = *(const short8*)&Ks[fj*16 + l15][kc*32 + l4*8];
      #pragma unroll
      for (int fi = 0; fi < 2; ++fi)
        #pragma unroll
        for (int fj = 0; fj < 4; ++fj)
          s[fi][fj] = __builtin_amdgcn_mfma_f32_16x16x32_bf16(qf[fi][kc], kf[fj], s[fi][fj], 0, 0, 0);
    }

    // online softmax (exp2 domain); row = fi*16 + l4*4 + r, cols spread over l15 x fj
    #pragma unroll
    for (int fi = 0; fi < 2; ++fi) {
      float rm[4];
      #pragma unroll
      for (int r = 0; r < 4; ++r)
        rm[r] = fmaxf(fmaxf(s[fi][0][r], s[fi][1][r]), fmaxf(s[fi][2][r], s[fi][3][r]));
      #pragma unroll
      for (int mk = 1; mk <= 8; mk <<= 1)
        #pragma unroll
        for (int r = 0; r < 4; ++r)
          rm[r] = fmaxf(rm[r], __shfl_xor(rm[r], mk, 64));
      float al[4];
      #pragma unroll
      for (int r = 0; r < 4; ++r) {
        const float mn = fmaxf(mm[fi][r], rm[r] * SCALE_LOG2E);
        al[r] = fast_exp2(mm[fi][r] - mn);
        mm[fi][r] = mn;
        ll[fi][r] *= al[r];
      }
      #pragma unroll
      for (int fj = 0; fj < 4; ++fj)
        #pragma unroll
        for (int r = 0; r < 4; ++r)
          o[fi][fj][r] *= al[r];
      float rs[4] = {0.f, 0.f, 0.f, 0.f};
      #pragma unroll
      for (int fj = 0; fj < 4; ++fj) {
        #pragma unroll
        for (int r = 0; r < 4; ++r) {
          const float p = fast_exp2(s[fi][fj][r] * SCALE_LOG2E - mm[fi][r]);
          rs[r] += p;
          Ps[w][fi*16 + l4*4 + r][l15 + fj*16] = bf16s(p);   // C-layout scatter
        }
      }
      #pragma unroll
      for (int mk = 1; mk <= 8; mk <<= 1)
        #pragma unroll
        for (int r = 0; r < 4; ++r)
          rs[r] += __shfl_xor(rs[r], mk, 64);
      #pragma unroll
      for (int r = 0; r < 4; ++r) ll[fi][r] += rs[r];
    }

    // O += P V   (A-operand = P rows from Ps, B-operand = Vt rows from Vs)
    #pragma unroll
    for (int kc = 0; kc < 2; ++kc) {
      short8 pf[2], vf[4];
      #pragma unroll
      for (int fi = 0; fi < 2; ++fi)
        pf[fi] = *(const short8*)&Ps[w][fi*16 + l15][kc*32 + l4*8];
      #pragma unroll
      for (int fj = 0; fj < 4; ++fj)
        vf[fj] = *(const short8*)&Vs[fj*16 + l15][kc*32 + l4*8];
      #pragma unroll
      for (int fi = 0; fi < 2; ++fi)
        #pragma unroll
        for (int fj = 0; fj < 4; ++fj)
          o[fi][fj] = __builtin_amdgcn_mfma_f32_16x16x32_bf16(pf[fi], vf[fj], o[fi][fj], 0, 0, 0);
    }
    __syncthreads();   // protect Ks/Vs before next stage
  }

  #pragma unroll
  for (int fi = 0; fi < 2; ++fi) {
    float inv[4];
    #pragma unroll
    for (int r = 0; r < 4; ++r) inv[r] = 1.0f / ll[fi][r];
    #pragma unroll
    for (int fj = 0; fj < 4; ++fj)
      #pragma unroll
      for (int r = 0; r < 4; ++r) {
        const int n = q0 + w*32 + fi*16 + l4*4 + r;
        const int d = h*64 + fj*16 + l15;
        AO[(size_t)(b*SEQ + n)*D_MODEL + d] = __float2bfloat16(o[fi][fj][r] * inv[r]);
      }
  }
}

extern "C" void kernel_launch(void* const* d_in, const int* in_sizes, int n_in,
                              void* d_out, int out_size, void* d_ws, size_t ws_size,
                              hipStream_t stream)
{
  const float* query = (const float*)d_in[0];
  const float* key_  = (const float*)d_in[1];
  const float* value = (const float*)d_in[2];
  const float* Wq = (const float*)d_in[3];
  const float* Wk = (const float*)d_in[4];
  const float* Wv = (const float*)d_in[5];
  const float* Wo = (const float*)d_in[6];
  const float* bo = (const float*)d_in[7];

  // ws: 4 x 8 MiB bf16 buffers (Q, K, Vt, attn_out) = 32 MiB total
  char* wsb = (char*)d_ws;
  short* Qp = (short*)(wsb);
  short* Kp = (short*)(wsb + (8u  << 20));
  short* Vp = (short*)(wsb + (16u << 20));
  short* Ao = (short*)(wsb + (24u << 20));

  dim3 gg(D_MODEL / 64, (2 * SEQ) / 128);   // 16 x 32 = 512 blocks
  gemm_bt<0><<<gg, 256, 0, stream>>>(query, Wq, nullptr, Qp);
  gemm_bt<0><<<gg, 256, 0, stream>>>(key_,  Wk, nullptr, Kp);
  gemm_bt<1><<<gg, 256, 0, stream>>>(value, Wv, nullptr, Vp);

  dim3 ga(SEQ / 128, 2 * NH);               // 16 x 32 = 512 blocks
  attn_fwd<<<ga, 256, 0, stream>>>(Qp, Kp, Vp, (__hip_bfloat16*)Ao);

  gemm_bt<2><<<gg, 256, 0, stream>>>(Ao, Wo, bo, d_out);
}

// Round 3
// 328.464 us; speedup vs baseline: 1.1796x; 1.1796x over previous
//
#include <hip/hip_runtime.h>
#include <hip/hip_bf16.h>

typedef __attribute__((ext_vector_type(8))) short short8;
typedef __attribute__((ext_vector_type(4))) short short4v;
typedef __attribute__((ext_vector_type(4))) float f32x4;

#define DEVFN static __device__ __forceinline__

constexpr int D_MODEL = 1024;
constexpr int NH  = 16;
constexpr int DH  = 64;
constexpr int SEQ = 2048;
constexpr float SCALE_LOG2E = 0.125f * 1.44269504088896341f;

DEVFN short bf16s(float f) {
  __hip_bfloat16 h = __float2bfloat16(f);
  short s; __builtin_memcpy(&s, &h, 2);
  return s;
}

DEVFN float fast_exp2(float x) {
#if __has_builtin(__builtin_amdgcn_exp2f)
  return __builtin_amdgcn_exp2f(x);
#else
  return exp2f(x);
#endif
}

// ---------------- cast f32 -> bf16 (optionally scaled), 8 elems/thread ------
__global__ __launch_bounds__(256)
void castk(const float* __restrict__ src, short* __restrict__ dst, int n8, float scale)
{
  int i = blockIdx.x * blockDim.x + threadIdx.x;
  if (i >= n8) return;
  const float4 a = *(const float4*)(src + (size_t)i*8);
  const float4 b = *(const float4*)(src + (size_t)i*8 + 4);
  short8 v;
  v[0]=bf16s(a.x*scale); v[1]=bf16s(a.y*scale); v[2]=bf16s(a.z*scale); v[3]=bf16s(a.w*scale);
  v[4]=bf16s(b.x*scale); v[5]=bf16s(b.y*scale); v[6]=bf16s(b.z*scale); v[7]=bf16s(b.w*scale);
  *(short8*)(dst + (size_t)i*8) = v;
}

// ---------------- bf16 GEMM: C = A @ W^T (both bf16, K contiguous) ----------
// BM=128 BN=64 BK=64, 4 waves (2x1 over 64x32 sub-tiles... wave: 64x32 out).
// XOR-swizzled LDS (reg-staged writes). MODE epilogues as gemm_bt.
template<int MODE>
__global__ __launch_bounds__(256, 4)
void gemm_bb(const short* __restrict__ A, const short* __restrict__ W,
             const float* __restrict__ bias, void* __restrict__ Cp)
{
  __shared__ short As[128*64];
  __shared__ short Ws[64*64];
  char* AsB = (char*)As; char* WsB = (char*)Ws;

  const int tid = threadIdx.x, lane = tid & 63;
  const int w = tid >> 6, wr = w >> 1, wc = w & 1;
  const int l15 = lane & 15, l4 = lane >> 4;
  const int m0 = blockIdx.y * 128, n0 = blockIdx.x * 64;

  f32x4 acc[4][2];
  #pragma unroll
  for (int i = 0; i < 4; ++i)
    #pragma unroll
    for (int j = 0; j < 2; ++j) acc[i][j] = f32x4{0.f,0.f,0.f,0.f};

  for (int kt = 0; kt < D_MODEL/64; ++kt) {
    const int k0 = kt * 64;
    #pragma unroll
    for (int i = 0; i < 4; ++i) {          // A: 128x64 shorts = 1024 chunks
      const int c = i*256 + tid, row = c >> 3, co = c & 7;
      short8 v = *(const short8*)(A + (size_t)(m0 + row)*D_MODEL + k0 + co*8);
      *(short8*)(AsB + ((row*128 + co*16) ^ ((row&7)<<4))) = v;
    }
    #pragma unroll
    for (int i = 0; i < 2; ++i) {          // W: 64x64 shorts = 512 chunks
      const int c = i*256 + tid, row = c >> 3, co = c & 7;
      short8 v = *(const short8*)(W + (size_t)(n0 + row)*D_MODEL + k0 + co*8);
      *(short8*)(WsB + ((row*128 + co*16) ^ ((row&7)<<4))) = v;
    }
    __syncthreads();
    #pragma unroll
    for (int kc = 0; kc < 2; ++kc) {
      short8 af[4], bf[2];
      #pragma unroll
      for (int fi = 0; fi < 4; ++fi) {
        const int row = wr*64 + fi*16 + l15;
        af[fi] = *(const short8*)(AsB + ((row*128 + (kc*32 + l4*8)*2) ^ ((row&7)<<4)));
      }
      #pragma unroll
      for (int fj = 0; fj < 2; ++fj) {
        const int row = wc*32 + fj*16 + l15;
        bf[fj] = *(const short8*)(WsB + ((row*128 + (kc*32 + l4*8)*2) ^ ((row&7)<<4)));
      }
      #pragma unroll
      for (int fi = 0; fi < 4; ++fi)
        #pragma unroll
        for (int fj = 0; fj < 2; ++fj)
          acc[fi][fj] = __builtin_amdgcn_mfma_f32_16x16x32_bf16(af[fi], bf[fj], acc[fi][fj], 0, 0, 0);
    }
    __syncthreads();
  }

  #pragma unroll
  for (int fi = 0; fi < 4; ++fi)
    #pragma unroll
    for (int fj = 0; fj < 2; ++fj)
      #pragma unroll
      for (int r = 0; r < 4; ++r) {
        const int m = m0 + wr*64 + fi*16 + l4*4 + r;
        const int j = n0 + wc*32 + fj*16 + l15;
        const float v = acc[fi][fj][r];
        if (MODE == 0) {
          const int b = m >> 11, n = m & (SEQ-1);
          const int h = j >> 6,  d = j & 63;
          ((__hip_bfloat16*)Cp)[(((size_t)(b*NH + h)*SEQ + n) << 6) + d] = __float2bfloat16(v);
        } else if (MODE == 1) {
          const int b = m >> 11, n = m & (SEQ-1);
          const int h = j >> 6,  d = j & 63;
          ((__hip_bfloat16*)Cp)[((size_t)(b*NH + h)*DH + d)*SEQ + n] = __float2bfloat16(v);
        } else {
          ((float*)Cp)[(size_t)m*D_MODEL + j] = v + bias[j];
        }
      }
}

// ---------------- f32-input GEMM (fallback path, inline cvt) ----------------
template<int MODE>
__global__ __launch_bounds__(256)
void gemm_bt(const void* __restrict__ Ap, const float* __restrict__ Bp,
             const float* __restrict__ bias, void* __restrict__ Cp, float scale)
{
  constexpr int BM = 128, BN = 64, BK = 32;
  __shared__ short As[BM][BK + 8];
  __shared__ short Bs[BN][BK + 8];

  const int tid = threadIdx.x, lane = tid & 63;
  const int w = tid >> 6, wr = w >> 1, wc = w & 1;
  const int m0 = blockIdx.y * BM, n0 = blockIdx.x * BN;
  const int l15 = lane & 15, l4 = lane >> 4;

  f32x4 acc[4][2];
  #pragma unroll
  for (int i = 0; i < 4; ++i)
    #pragma unroll
    for (int j = 0; j < 2; ++j) acc[i][j] = f32x4{0.f,0.f,0.f,0.f};

  const int sr = tid >> 3, sc = (tid & 7) * 4;

  for (int kt = 0; kt < D_MODEL / BK; ++kt) {
    const int k0 = kt * BK;
    if (MODE == 2) {
      const short* Ab = (const short*)Ap;
      const int ar = tid >> 2, ac = (tid & 3) * 8;
      #pragma unroll
      for (int p = 0; p < 2; ++p) {
        short8 v = *(const short8*)(Ab + (size_t)(m0 + ar + p*64)*D_MODEL + k0 + ac);
        *(short8*)&As[ar + p*64][ac] = v;
      }
    } else {
      const float* Af = (const float*)Ap;
      #pragma unroll
      for (int p = 0; p < 4; ++p) {
        const float4 v = *(const float4*)(Af + (size_t)(m0 + sr + p*32)*D_MODEL + k0 + sc);
        short4v pk;
        pk[0]=bf16s(v.x); pk[1]=bf16s(v.y); pk[2]=bf16s(v.z); pk[3]=bf16s(v.w);
        *(short4v*)&As[sr + p*32][sc] = pk;
      }
    }
    #pragma unroll
    for (int p = 0; p < 2; ++p) {
      const float4 v = *(const float4*)(Bp + (size_t)(n0 + sr + p*32)*D_MODEL + k0 + sc);
      short4v pk;
      pk[0]=bf16s(v.x); pk[1]=bf16s(v.y); pk[2]=bf16s(v.z); pk[3]=bf16s(v.w);
      *(short4v*)&Bs[sr + p*32][sc] = pk;
    }
    __syncthreads();

    short8 af[4], bf[2];
    #pragma unroll
    for (int fi = 0; fi < 4; ++fi)
      af[fi] = *(const short8*)&As[wr*64 + fi*16 + l15][l4*8];
    #pragma unroll
    for (int fj = 0; fj < 2; ++fj)
      bf[fj] = *(const short8*)&Bs[wc*32 + fj*16 + l15][l4*8];
    #pragma unroll
    for (int fi = 0; fi < 4; ++fi)
      #pragma unroll
      for (int fj = 0; fj < 2; ++fj)
        acc[fi][fj] = __builtin_amdgcn_mfma_f32_16x16x32_bf16(af[fi], bf[fj], acc[fi][fj], 0, 0, 0);
    __syncthreads();
  }

  #pragma unroll
  for (int fi = 0; fi < 4; ++fi)
    #pragma unroll
    for (int fj = 0; fj < 2; ++fj)
      #pragma unroll
      for (int r = 0; r < 4; ++r) {
        const int m = m0 + wr*64 + fi*16 + l4*4 + r;
        const int j = n0 + wc*32 + fj*16 + l15;
        const float v = acc[fi][fj][r];
        if (MODE == 0) {
          const int b = m >> 11, n = m & (SEQ-1);
          const int h = j >> 6,  d = j & 63;
          ((__hip_bfloat16*)Cp)[(((size_t)(b*NH + h)*SEQ + n) << 6) + d] = __float2bfloat16(v*scale);
        } else if (MODE == 1) {
          const int b = m >> 11, n = m & (SEQ-1);
          const int h = j >> 6,  d = j & 63;
          ((__hip_bfloat16*)Cp)[((size_t)(b*NH + h)*DH + d)*SEQ + n] = __float2bfloat16(v*scale);
        } else {
          ((float*)Cp)[(size_t)m*D_MODEL + j] = v + bias[j];
        }
      }
}

// ---------------- Flash attention, swapped QK^T -----------------------------
// Qh (PRE-SCALED by SCALE*log2e): bf16 [B*H][SEQ][64]; Kh same layout;
// Vt: bf16 [B*H][64][SEQ]. AO: bf16 [B][SEQ][1024].
// 8 waves/block; wave owns 16 q-rows; lane owns q-row l15 (dup over l4).
__global__ __launch_bounds__(512, 4)
void attn_fwd(const short* __restrict__ Qh, const short* __restrict__ Kh,
              const short* __restrict__ Vt, __hip_bfloat16* __restrict__ AO)
{
  __shared__ short Ks[64*64];       // [kv][d] swizzled
  __shared__ short Vs[64*64];       // [d][kv] swizzled
  __shared__ short Ps[8*16*64];     // per-wave P [q16][kv64] swizzled
  char* KsB = (char*)Ks; char* VsB = (char*)Vs;

  const int tid = threadIdx.x, lane = tid & 63, w = tid >> 6;
  const int l15 = lane & 15, l4 = lane >> 4;
  const int bh = blockIdx.y, q0 = blockIdx.x * 128;
  const int b = bh >> 4, h = bh & 15;
  const size_t base = (size_t)bh * SEQ * DH;
  char* PsB = (char*)(Ps + w * 16 * 64);

  // Q fragments (B-operand: row = q = l15, k = kc*32 + l4*8)
  short8 qf[2];
  #pragma unroll
  for (int kc = 0; kc < 2; ++kc)
    qf[kc] = *(const short8*)(Qh + base + (size_t)(q0 + w*16 + l15)*DH + kc*32 + l4*8);

  float m = -1e30f, l = 0.f;
  f32x4 o[4];
  #pragma unroll
  for (int fj = 0; fj < 4; ++fj) o[fj] = f32x4{0.f,0.f,0.f,0.f};

  const int srow = tid >> 3;                 // 0..63
  const int sco  = tid & 7;                  // 16B chunk
  const int sdst = (srow*128 + sco*16) ^ ((srow&7)<<4);

  for (int kt = 0; kt < SEQ/64; ++kt) {
    // stage K [kv][d] and Vt [d][kv] tiles, swizzled
    short8 kv_ = *(const short8*)(Kh + base + (size_t)(kt*64 + srow)*DH + sco*8);
    short8 vv_ = *(const short8*)(Vt + base + (size_t)srow*SEQ + kt*64 + sco*8);
    *(short8*)(KsB + sdst) = kv_;
    *(short8*)(VsB + sdst) = vv_;
    __syncthreads();

    // S^T = K Q^T : lane holds S[q=l15][kv = fj*16 + l4*4 + r]
    f32x4 s[4];
    #pragma unroll
    for (int fj = 0; fj < 4; ++fj) s[fj] = f32x4{0.f,0.f,0.f,0.f};
    #pragma unroll
    for (int kc = 0; kc < 2; ++kc)
      #pragma unroll
      for (int fj = 0; fj < 4; ++fj) {
        const int row = fj*16 + l15;
        short8 kf = *(const short8*)(KsB + ((row*128 + (kc*32 + l4*8)*2) ^ ((row&7)<<4)));
        s[fj] = __builtin_amdgcn_mfma_f32_16x16x32_bf16(kf, qf[kc], s[fj], 0, 0, 0);
      }

    // online softmax: row-local chain + 2 shfl_xor (reduce over l4 groups)
    float pmax = s[0][0];
    #pragma unroll
    for (int fj = 0; fj < 4; ++fj)
      #pragma unroll
      for (int r = 0; r < 4; ++r) pmax = fmaxf(pmax, s[fj][r]);
    pmax = fmaxf(pmax, __shfl_xor(pmax, 16, 64));
    pmax = fmaxf(pmax, __shfl_xor(pmax, 32, 64));
    const float mn = fmaxf(m, pmax);
    const float al = fast_exp2(m - mn);
    m = mn;
    float rs = 0.f;
    #pragma unroll
    for (int fj = 0; fj < 4; ++fj)
      #pragma unroll
      for (int r = 0; r < 4; ++r) {
        s[fj][r] = fast_exp2(s[fj][r] - m);
        rs += s[fj][r];
      }
    rs += __shfl_xor(rs, 16, 64);
    rs += __shfl_xor(rs, 32, 64);
    l = l * al + rs;

    // P -> per-wave LDS (bf16, swizzled); same-wave ordering, no barrier
    #pragma unroll
    for (int fj = 0; fj < 4; ++fj) {
      short4v c;
      c[0]=bf16s(s[fj][0]); c[1]=bf16s(s[fj][1]); c[2]=bf16s(s[fj][2]); c[3]=bf16s(s[fj][3]);
      const int byo = (l15*128 + (fj*16 + l4*4)*2) ^ ((l15&7)<<4);
      *(short4v*)(PsB + byo) = c;
    }

    // rescale O by al (al lives at lane l15=q; O rows are q=l4*4+r)
    float alr[4];
    #pragma unroll
    for (int r = 0; r < 4; ++r) alr[r] = __shfl(al, l4*4 + r, 64);
    #pragma unroll
    for (int fj = 0; fj < 4; ++fj)
      #pragma unroll
      for (int r = 0; r < 4; ++r) o[fj][r] *= alr[r];

    // O += P V : A = P rows (q), B = Vt rows (d)
    #pragma unroll
    for (int kc = 0; kc < 2; ++kc) {
      const int pb = (l15*128 + (kc*32 + l4*8)*2) ^ ((l15&7)<<4);
      short8 pa = *(const short8*)(PsB + pb);
      #pragma unroll
      for (int fj = 0; fj < 4; ++fj) {
        const int row = fj*16 + l15;
        short8 vf = *(const short8*)(VsB + ((row*128 + (kc*32 + l4*8)*2) ^ ((row&7)<<4)));
        o[fj] = __builtin_amdgcn_mfma_f32_16x16x32_bf16(pa, vf, o[fj], 0, 0, 0);
      }
    }
    __syncthreads();   // protect Ks/Vs for next stage
  }

  const float inv = 1.0f / l;
  float ivr[4];
  #pragma unroll
  for (int r = 0; r < 4; ++r) ivr[r] = __shfl(inv, l4*4 + r, 64);
  #pragma unroll
  for (int fj = 0; fj < 4; ++fj)
    #pragma unroll
    for (int r = 0; r < 4; ++r) {
      const int n = q0 + w*16 + l4*4 + r;
      const int d = h*64 + fj*16 + l15;
      AO[(size_t)(b*SEQ + n)*D_MODEL + d] = __float2bfloat16(o[fj][r] * ivr[r]);
    }
}

extern "C" void kernel_launch(void* const* d_in, const int* in_sizes, int n_in,
                              void* d_out, int out_size, void* d_ws, size_t ws_size,
                              hipStream_t stream)
{
  const float* query = (const float*)d_in[0];
  const float* key_  = (const float*)d_in[1];
  const float* value = (const float*)d_in[2];
  const float* Wq = (const float*)d_in[3];
  const float* Wk = (const float*)d_in[4];
  const float* Wv = (const float*)d_in[5];
  const float* Wo = (const float*)d_in[6];
  const float* bo = (const float*)d_in[7];

  char* wsb = (char*)d_ws;
  dim3 gg(D_MODEL/64, (2*SEQ)/128);      // 16 x 32 = 512 blocks
  dim3 ga(SEQ/128, 2*NH);                // 16 x 32 = 512 blocks

  if (ws_size >= (size_t)(56u << 20)) {
    // fat path: pre-cast everything to bf16, pure-bf16 GEMMs
    short* Qb  = (short*)(wsb);               // 8M  (reused for Ao later)
    short* Kb  = (short*)(wsb + (8u  << 20));
    short* Vb  = (short*)(wsb + (16u << 20));
    short* Wqb = (short*)(wsb + (24u << 20));
    short* Wkb = (short*)(wsb + (26u << 20));
    short* Wvb = (short*)(wsb + (28u << 20));
    short* Wob = (short*)(wsb + (30u << 20));
    short* Qp  = (short*)(wsb + (32u << 20));
    short* Kp  = (short*)(wsb + (40u << 20));
    short* Vp  = (short*)(wsb + (48u << 20));
    short* Ao  = Qb;                          // Qb dead after Q projection

    const int nI = 4096*1024/8, nW = 1024*1024/8;
    castk<<<nI/256, 256, 0, stream>>>(query, Qb, nI, 1.f);
    castk<<<nI/256, 256, 0, stream>>>(key_,  Kb, nI, 1.f);
    castk<<<nI/256, 256, 0, stream>>>(value, Vb, nI, 1.f);
    castk<<<nW/256, 256, 0, stream>>>(Wq, Wqb, nW, SCALE_LOG2E);  // pre-scale Q path
    castk<<<nW/256, 256, 0, stream>>>(Wk, Wkb, nW, 1.f);
    castk<<<nW/256, 256, 0, stream>>>(Wv, Wvb, nW, 1.f);
    castk<<<nW/256, 256, 0, stream>>>(Wo, Wob, nW, 1.f);

    gemm_bb<0><<<gg, 256, 0, stream>>>(Qb, Wqb, nullptr, Qp);
    gemm_bb<0><<<gg, 256, 0, stream>>>(Kb, Wkb, nullptr, Kp);
    gemm_bb<1><<<gg, 256, 0, stream>>>(Vb, Wvb, nullptr, Vp);
    attn_fwd<<<ga, 512, 0, stream>>>(Qp, Kp, Vp, (__hip_bfloat16*)Ao);
    gemm_bb<2><<<gg, 256, 0, stream>>>(Ao, Wob, bo, d_out);
  } else {
    // lean path (>=32M): f32-input GEMMs with inline cvt
    short* Qp = (short*)(wsb);
    short* Kp = (short*)(wsb + (8u  << 20));
    short* Vp = (short*)(wsb + (16u << 20));
    short* Ao = (short*)(wsb + (24u << 20));

    gemm_bt<0><<<gg, 256, 0, stream>>>(query, Wq, nullptr, Qp, SCALE_LOG2E);
    gemm_bt<0><<<gg, 256, 0, stream>>>(key_,  Wk, nullptr, Kp, 1.f);
    gemm_bt<1><<<gg, 256, 0, stream>>>(value, Wv, nullptr, Vp, 1.f);
    attn_fwd<<<ga, 512, 0, stream>>>(Qp, Kp, Vp, (__hip_bfloat16*)Ao);
    gemm_bt<2><<<gg, 256, 0, stream>>>(Ao, Wo, bo, d_out, 1.f);
  }
}

// Round 5
// 254.272 us; speedup vs baseline: 1.5238x; 1.2918x over previous
//
#include <hip/hip_runtime.h>
#include <hip/hip_bf16.h>

typedef __attribute__((ext_vector_type(8))) short short8;
typedef __attribute__((ext_vector_type(4))) short short4v;
typedef __attribute__((ext_vector_type(4))) float f32x4;

#define DEVFN static __device__ __forceinline__

constexpr int D_MODEL = 1024;
constexpr int NH  = 16;
constexpr int DH  = 64;
constexpr int SEQ = 2048;
constexpr float SCALE_LOG2E = 0.125f * 1.44269504088896341f;

DEVFN short bf16s(float f) {
  __hip_bfloat16 h = __float2bfloat16(f);
  short s; __builtin_memcpy(&s, &h, 2);
  return s;
}

DEVFN float fast_exp2(float x) {
#if __has_builtin(__builtin_amdgcn_exp2f)
  return __builtin_amdgcn_exp2f(x);
#else
  return exp2f(x);
#endif
}

// async global->LDS, 16B per lane. LDS dest is wave-uniform base + lane*16.
DEVFN void gload_lds16(const void* g, void* l) {
  __builtin_amdgcn_global_load_lds(
      (const __attribute__((address_space(1))) unsigned int*)g,
      (__attribute__((address_space(3))) unsigned int*)l, 16, 0, 0);
}

// ---------------- cast f32 -> bf16 (optionally scaled), 8 elems/thread ------
__global__ __launch_bounds__(256)
void castk(const float* __restrict__ src, short* __restrict__ dst, int n8, float scale)
{
  int i = blockIdx.x * blockDim.x + threadIdx.x;
  if (i >= n8) return;
  const float4 a = *(const float4*)(src + (size_t)i*8);
  const float4 b = *(const float4*)(src + (size_t)i*8 + 4);
  short8 v;
  v[0]=bf16s(a.x*scale); v[1]=bf16s(a.y*scale); v[2]=bf16s(a.z*scale); v[3]=bf16s(a.w*scale);
  v[4]=bf16s(b.x*scale); v[5]=bf16s(b.y*scale); v[6]=bf16s(b.z*scale); v[7]=bf16s(b.w*scale);
  *(short8*)(dst + (size_t)i*8) = v;
}

// ---------------- fused QKV projection ---------------------------------------
// z=0: Qp = query @ Wqb^T (Wqb pre-scaled by SCALE*log2e), per-head [B,H,S,DH]
// z=1: Kp = key   @ Wkb^T, per-head layout
// z=2: Vp = value @ Wvb^T, transposed  [B,H,DH,S]
// A is f32, staged via global_load_lds (pre-swizzled source), cvt at frag read.
// W is bf16. BM=BN=128, BK=32, 4 waves, wave = 64x64 out.
__global__ __launch_bounds__(256, 3)
void qkv_gemm(const float* __restrict__ Aq, const float* __restrict__ Ak,
              const float* __restrict__ Av,
              const short* __restrict__ Wq, const short* __restrict__ Wk,
              const short* __restrict__ Wv,
              short* __restrict__ Qp, short* __restrict__ Kp, short* __restrict__ Vp)
{
  __shared__ char smem[16384 + 8192];   // As f32 [128][32] + Ws bf16 [128][32]
  char* AsB = smem;
  char* WsB = smem + 16384;

  const int z = blockIdx.z;
  const float* Af = (z == 0) ? Aq : (z == 1) ? Ak : Av;
  const short* Wb = (z == 0) ? Wq : (z == 1) ? Wk : Wv;
  short* Cp       = (z == 0) ? Qp : (z == 1) ? Kp : Vp;

  const int tid = threadIdx.x, lane = tid & 63, w = tid >> 6;
  const int wr = w >> 1, wc = w & 1;
  const int l15 = lane & 15, l4 = lane >> 4;
  const int m0 = blockIdx.y * 128, n0 = blockIdx.x * 128;

  f32x4 acc[4][4];
  #pragma unroll
  for (int i = 0; i < 4; ++i)
    #pragma unroll
    for (int j = 0; j < 4; ++j) acc[i][j] = f32x4{0.f,0.f,0.f,0.f};

  for (int kt = 0; kt < D_MODEL/32; ++kt) {
    const int k0 = kt * 32;
    // A tile f32 [128][32], rows 128B, swizzle byte ^= (row&7)<<4 (via source)
    #pragma unroll
    for (int p = 0; p < 4; ++p) {
      const int off = (w*4 + p)*1024 + lane*16;
      const int row = off >> 7;
      const int cb  = (off & 127) ^ ((row & 7) << 4);
      gload_lds16(Af + (size_t)(m0 + row)*D_MODEL + k0 + (cb >> 2),
                  AsB + (w*4 + p)*1024);
    }
    // W tile bf16 [128][32], rows 64B, swizzle byte ^= (row&3)<<4
    #pragma unroll
    for (int p = 0; p < 2; ++p) {
      const int off = (w*2 + p)*1024 + lane*16;
      const int row = off >> 6;
      const int cb  = (off & 63) ^ ((row & 3) << 4);
      gload_lds16(Wb + (size_t)(n0 + row)*D_MODEL + k0 + (cb >> 1),
                  WsB + (w*2 + p)*1024);
    }
    __syncthreads();

    short8 af[4], bf[4];
    #pragma unroll
    for (int fi = 0; fi < 4; ++fi) {
      const int row = wr*64 + fi*16 + l15;
      const int s_ = (row & 7) << 4;
      f32x4 x0 = *(const f32x4*)(AsB + row*128 + ((l4*32) ^ s_));
      f32x4 x1 = *(const f32x4*)(AsB + row*128 + ((l4*32 + 16) ^ s_));
      short8 a;
      a[0]=bf16s(x0[0]); a[1]=bf16s(x0[1]); a[2]=bf16s(x0[2]); a[3]=bf16s(x0[3]);
      a[4]=bf16s(x1[0]); a[5]=bf16s(x1[1]); a[6]=bf16s(x1[2]); a[7]=bf16s(x1[3]);
      af[fi] = a;
    }
    #pragma unroll
    for (int fj = 0; fj < 4; ++fj) {
      const int row = wc*64 + fj*16 + l15;
      bf[fj] = *(const short8*)(WsB + row*64 + ((l4*16) ^ ((row & 3) << 4)));
    }
    #pragma unroll
    for (int fi = 0; fi < 4; ++fi)
      #pragma unroll
      for (int fj = 0; fj < 4; ++fj)
        acc[fi][fj] = __builtin_amdgcn_mfma_f32_16x16x32_bf16(af[fi], bf[fj], acc[fi][fj], 0, 0, 0);
    __syncthreads();
  }

  // epilogue: per-head scatter
  #pragma unroll
  for (int fi = 0; fi < 4; ++fi)
    #pragma unroll
    for (int fj = 0; fj < 4; ++fj)
      #pragma unroll
      for (int r = 0; r < 4; ++r) {
        const int m = m0 + wr*64 + fi*16 + l4*4 + r;
        const int j = n0 + wc*64 + fj*16 + l15;
        const int b = m >> 11, n = m & (SEQ-1);
        const int h = j >> 6,  d = j & 63;
        const short v = bf16s(acc[fi][fj][r]);
        if (z == 2)
          Cp[((size_t)(b*NH + h)*DH + d)*SEQ + n] = v;          // V^T
        else
          Cp[(((size_t)(b*NH + h)*SEQ + n) << 6) + d] = v;      // per-head
      }
}

// ---------------- output GEMM: d_out = Ao @ Wo^T + bias (all bf16 in) -------
// BM=128, BN=64, BK=32, 4 waves, wave = 64x32 out. grid (16,32).
__global__ __launch_bounds__(256, 4)
void gemm_out(const short* __restrict__ A, const short* __restrict__ Wb,
              const float* __restrict__ bias, float* __restrict__ Cp)
{
  __shared__ char smem[8192 + 4096];    // As bf16 [128][32] + Ws bf16 [64][32]
  char* AsB = smem;
  char* WsB = smem + 8192;

  const int tid = threadIdx.x, lane = tid & 63, w = tid >> 6;
  const int wr = w >> 1, wc = w & 1;
  const int l15 = lane & 15, l4 = lane >> 4;
  const int m0 = blockIdx.y * 128, n0 = blockIdx.x * 64;

  f32x4 acc[4][2];
  #pragma unroll
  for (int i = 0; i < 4; ++i)
    #pragma unroll
    for (int j = 0; j < 2; ++j) acc[i][j] = f32x4{0.f,0.f,0.f,0.f};

  for (int kt = 0; kt < D_MODEL/32; ++kt) {
    const int k0 = kt * 32;
    #pragma unroll
    for (int p = 0; p < 2; ++p) {       // A: 8 KB
      const int off = (w*2 + p)*1024 + lane*16;
      const int row = off >> 6;
      const int cb  = (off & 63) ^ ((row & 3) << 4);
      gload_lds16(A + (size_t)(m0 + row)*D_MODEL + k0 + (cb >> 1),
                  AsB + (w*2 + p)*1024);
    }
    {                                    // W: 4 KB
      const int off = w*1024 + lane*16;
      const int row = off >> 6;
      const int cb  = (off & 63) ^ ((row & 3) << 4);
      gload_lds16(Wb + (size_t)(n0 + row)*D_MODEL + k0 + (cb >> 1),
                  WsB + w*1024);
    }
    __syncthreads();

    short8 af[4], bf[2];
    #pragma unroll
    for (int fi = 0; fi < 4; ++fi) {
      const int row = wr*64 + fi*16 + l15;
      af[fi] = *(const short8*)(AsB + row*64 + ((l4*16) ^ ((row & 3) << 4)));
    }
    #pragma unroll
    for (int fj = 0; fj < 2; ++fj) {
      const int row = wc*32 + fj*16 + l15;
      bf[fj] = *(const short8*)(WsB + row*64 + ((l4*16) ^ ((row & 3) << 4)));
    }
    #pragma unroll
    for (int fi = 0; fi < 4; ++fi)
      #pragma unroll
      for (int fj = 0; fj < 2; ++fj)
        acc[fi][fj] = __builtin_amdgcn_mfma_f32_16x16x32_bf16(af[fi], bf[fj], acc[fi][fj], 0, 0, 0);
    __syncthreads();
  }

  float bj[2];
  #pragma unroll
  for (int fj = 0; fj < 2; ++fj) bj[fj] = bias[n0 + wc*32 + fj*16 + l15];
  #pragma unroll
  for (int fi = 0; fi < 4; ++fi)
    #pragma unroll
    for (int fj = 0; fj < 2; ++fj)
      #pragma unroll
      for (int r = 0; r < 4; ++r) {
        const int m = m0 + wr*64 + fi*16 + l4*4 + r;
        const int j = n0 + wc*32 + fj*16 + l15;
        Cp[(size_t)m*D_MODEL + j] = acc[fi][fj][r] + bj[fj];
      }
}

// ---------------- Flash attention, swapped QK^T, T14 dbuf -------------------
// Qh (PRE-SCALED): bf16 [B*H][SEQ][64]; Kh same; Vt: bf16 [B*H][64][SEQ].
// AO: bf16 [B][SEQ][1024]. 8 waves; wave owns 16 q-rows (lane l15 = q-row).
__global__ __launch_bounds__(512, 2)
void attn_fwd(const short* __restrict__ Qh, const short* __restrict__ Kh,
              const short* __restrict__ Vt, __hip_bfloat16* __restrict__ AO)
{
  __shared__ char smem[49152];   // K/V dbuf: [2][8KB K + 8KB V] + Ps 16KB
  char* PsAll = smem + 32768;

  const int tid = threadIdx.x, lane = tid & 63, w = tid >> 6;
  const int l15 = lane & 15, l4 = lane >> 4;
  const int bh = blockIdx.y, q0 = blockIdx.x * 128;
  const int b = bh >> 4, h = bh & 15;
  const size_t base = (size_t)bh * SEQ * DH;
  char* PsB = PsAll + w * 2048;

  const short* Kg = Kh + base;
  const short* Vg = Vt + base;

  short8 qf[2];
  #pragma unroll
  for (int kc = 0; kc < 2; ++kc)
    qf[kc] = *(const short8*)(Qh + base + (size_t)(q0 + w*16 + l15)*DH + kc*32 + l4*8);

  float m = -1e30f, l = 0.f;
  f32x4 o[4];
  #pragma unroll
  for (int fj = 0; fj < 4; ++fj) o[fj] = f32x4{0.f,0.f,0.f,0.f};

  const int srow = tid >> 3, sco = tid & 7;
  const int sdst = (srow*128 + sco*16) ^ ((srow & 7) << 4);

  // prologue: stage tile 0 into buf 0
  short8 kr = *(const short8*)(Kg + (size_t)srow*DH + sco*8);
  short8 vr = *(const short8*)(Vg + (size_t)srow*SEQ + sco*8);
  *(short8*)(smem + sdst) = kr;
  *(short8*)(smem + 8192 + sdst) = vr;
  __syncthreads();

  constexpr int NT = SEQ/64;
  for (int kt = 0; kt < NT; ++kt) {
    const int cur = kt & 1;
    char* KsB = smem + cur*16384;
    char* VsB = KsB + 8192;

    // issue next tile's global loads early (latency hidden under compute)
    if (kt + 1 < NT) {
      kr = *(const short8*)(Kg + (size_t)((kt+1)*64 + srow)*DH + sco*8);
      vr = *(const short8*)(Vg + (size_t)srow*SEQ + (kt+1)*64 + sco*8);
    }

    // S^T = K Q^T : lane holds S[q=l15][kv = fj*16 + l4*4 + r]
    f32x4 s[4];
    #pragma unroll
    for (int fj = 0; fj < 4; ++fj) s[fj] = f32x4{0.f,0.f,0.f,0.f};
    #pragma unroll
    for (int kc = 0; kc < 2; ++kc)
      #pragma unroll
      for (int fj = 0; fj < 4; ++fj) {
        const int row = fj*16 + l15;
        short8 kf = *(const short8*)(KsB + ((row*128 + (kc*32 + l4*8)*2) ^ ((row & 7) << 4)));
        s[fj] = __builtin_amdgcn_mfma_f32_16x16x32_bf16(kf, qf[kc], s[fj], 0, 0, 0);
      }

    // online softmax (exp2 domain, Q pre-scaled)
    float pmax = s[0][0];
    #pragma unroll
    for (int fj = 0; fj < 4; ++fj)
      #pragma unroll
      for (int r = 0; r < 4; ++r) pmax = fmaxf(pmax, s[fj][r]);
    pmax = fmaxf(pmax, __shfl_xor(pmax, 16, 64));
    pmax = fmaxf(pmax, __shfl_xor(pmax, 32, 64));
    const float mn = fmaxf(m, pmax);
    const float al = fast_exp2(m - mn);
    m = mn;
    float rs = 0.f;
    #pragma unroll
    for (int fj = 0; fj < 4; ++fj)
      #pragma unroll
      for (int r = 0; r < 4; ++r) {
        s[fj][r] = fast_exp2(s[fj][r] - m);
        rs += s[fj][r];
      }
    rs += __shfl_xor(rs, 16, 64);
    rs += __shfl_xor(rs, 32, 64);
    l = l * al + rs;

    // P -> per-wave LDS (bf16, swizzled); same-wave ordering, no barrier
    #pragma unroll
    for (int fj = 0; fj < 4; ++fj) {
      short4v c;
      c[0]=bf16s(s[fj][0]); c[1]=bf16s(s[fj][1]); c[2]=bf16s(s[fj][2]); c[3]=bf16s(s[fj][3]);
      const int byo = (l15*128 + (fj*16 + l4*4)*2) ^ ((l15 & 7) << 4);
      *(short4v*)(PsB + byo) = c;
    }

    // rescale O by al
    float alr[4];
    #pragma unroll
    for (int r = 0; r < 4; ++r) alr[r] = __shfl(al, l4*4 + r, 64);
    #pragma unroll
    for (int fj = 0; fj < 4; ++fj)
      #pragma unroll
      for (int r = 0; r < 4; ++r) o[fj][r] *= alr[r];

    // O += P V
    #pragma unroll
    for (int kc = 0; kc < 2; ++kc) {
      const int pb = (l15*128 + (kc*32 + l4*8)*2) ^ ((l15 & 7) << 4);
      short8 pa = *(const short8*)(PsB + pb);
      #pragma unroll
      for (int fj = 0; fj < 4; ++fj) {
        const int row = fj*16 + l15;
        short8 vf = *(const short8*)(VsB + ((row*128 + (kc*32 + l4*8)*2) ^ ((row & 7) << 4)));
        o[fj] = __builtin_amdgcn_mfma_f32_16x16x32_bf16(pa, vf, o[fj], 0, 0, 0);
      }
    }

    // write next tile into the other buffer; single barrier per iteration
    if (kt + 1 < NT) {
      char* KnB = smem + (cur ^ 1)*16384;
      *(short8*)(KnB + sdst) = kr;
      *(short8*)(KnB + 8192 + sdst) = vr;
    }
    __syncthreads();
  }

  const float inv = 1.0f / l;
  float ivr[4];
  #pragma unroll
  for (int r = 0; r < 4; ++r) ivr[r] = __shfl(inv, l4*4 + r, 64);
  #pragma unroll
  for (int fj = 0; fj < 4; ++fj)
    #pragma unroll
    for (int r = 0; r < 4; ++r) {
      const int n = q0 + w*16 + l4*4 + r;
      const int d = h*64 + fj*16 + l15;
      AO[(size_t)(b*SEQ + n)*D_MODEL + d] = __float2bfloat16(o[fj][r] * ivr[r]);
    }
}

extern "C" void kernel_launch(void* const* d_in, const int* in_sizes, int n_in,
                              void* d_out, int out_size, void* d_ws, size_t ws_size,
                              hipStream_t stream)
{
  const float* query = (const float*)d_in[0];
  const float* key_  = (const float*)d_in[1];
  const float* value = (const float*)d_in[2];
  const float* Wq = (const float*)d_in[3];
  const float* Wk = (const float*)d_in[4];
  const float* Wv = (const float*)d_in[5];
  const float* Wo = (const float*)d_in[6];
  const float* bo = (const float*)d_in[7];

  // 32 MiB total (proven safe in round 2):
  // [0,8M): Qp  -> after attn: Wob at [0,2M)
  // [8,16M): Kp   [16,24M): Vp (V^T)
  // [24,32M): Wqb/Wkb/Wvb (2M each) -> after projections: Ao (8M)
  char* wsb = (char*)d_ws;
  short* Qp  = (short*)(wsb);
  short* Kp  = (short*)(wsb + (8u  << 20));
  short* Vp  = (short*)(wsb + (16u << 20));
  short* Wqb = (short*)(wsb + (24u << 20));
  short* Wkb = (short*)(wsb + (26u << 20));
  short* Wvb = (short*)(wsb + (28u << 20));
  short* Ao  = (short*)(wsb + (24u << 20));   // aliases weights (dead by then)
  short* Wob = (short*)(wsb);                 // aliases Qp (dead after attn)

  const int nW = D_MODEL*D_MODEL/8;
  castk<<<nW/256, 256, 0, stream>>>(Wq, Wqb, nW, SCALE_LOG2E);
  castk<<<nW/256, 256, 0, stream>>>(Wk, Wkb, nW, 1.f);
  castk<<<nW/256, 256, 0, stream>>>(Wv, Wvb, nW, 1.f);

  dim3 gq(D_MODEL/128, (2*SEQ)/128, 3);       // 8 x 32 x 3 = 768 blocks
  qkv_gemm<<<gq, 256, 0, stream>>>(query, key_, value, Wqb, Wkb, Wvb, Qp, Kp, Vp);

  dim3 ga(SEQ/128, 2*NH);                     // 16 x 32 = 512 blocks
  attn_fwd<<<ga, 512, 0, stream>>>(Qp, Kp, Vp, (__hip_bfloat16*)Ao);

  castk<<<nW/256, 256, 0, stream>>>(Wo, Wob, nW, 1.f);
  dim3 go(D_MODEL/64, (2*SEQ)/128);           // 16 x 32 = 512 blocks
  gemm_out<<<go, 256, 0, stream>>>(Ao, Wob, bo, (float*)d_out);
}

// Round 6
// 242.726 us; speedup vs baseline: 1.5963x; 1.0476x over previous
//
#include <hip/hip_runtime.h>
#include <hip/hip_bf16.h>

typedef __attribute__((ext_vector_type(8))) short short8;
typedef __attribute__((ext_vector_type(4))) short short4v;
typedef __attribute__((ext_vector_type(4))) float f32x4;

#define DEVFN static __device__ __forceinline__

constexpr int D_MODEL = 1024;
constexpr int NH  = 16;
constexpr int DH  = 64;
constexpr int SEQ = 2048;
constexpr float SCALE_LOG2E = 0.125f * 1.44269504088896341f;

DEVFN short bf16s(float f) {
  __hip_bfloat16 h = __float2bfloat16(f);
  short s; __builtin_memcpy(&s, &h, 2);
  return s;
}

DEVFN float fast_exp2(float x) {
#if __has_builtin(__builtin_amdgcn_exp2f)
  return __builtin_amdgcn_exp2f(x);
#else
  return exp2f(x);
#endif
}

DEVFN void wait_vm0() { asm volatile("s_waitcnt vmcnt(0)" ::: "memory"); }

// async global->LDS, 16B per lane. LDS dest is wave-uniform base + lane*16.
DEVFN void gload_lds16(const void* g, void* l) {
  __builtin_amdgcn_global_load_lds(
      (const __attribute__((address_space(1))) unsigned int*)g,
      (__attribute__((address_space(3))) unsigned int*)l, 16, 0, 0);
}

// ---------------- cast f32 -> bf16 (optionally scaled), 8 elems/thread ------
__global__ __launch_bounds__(256)
void castk(const float* __restrict__ src, short* __restrict__ dst, int n8, float scale)
{
  int i = blockIdx.x * blockDim.x + threadIdx.x;
  if (i >= n8) return;
  const float4 a = *(const float4*)(src + (size_t)i*8);
  const float4 b = *(const float4*)(src + (size_t)i*8 + 4);
  short8 v;
  v[0]=bf16s(a.x*scale); v[1]=bf16s(a.y*scale); v[2]=bf16s(a.z*scale); v[3]=bf16s(a.w*scale);
  v[4]=bf16s(b.x*scale); v[5]=bf16s(b.y*scale); v[6]=bf16s(b.z*scale); v[7]=bf16s(b.w*scale);
  *(short8*)(dst + (size_t)i*8) = v;
}

// ---------------- fused QKV projection ---------------------------------------
// 1D grid 768, XCD-swizzled. z=0:Q z=1:K (per-head [B,H,S,DH]); z=2:V^T.
// A f32 staged via global_load_lds (pre-swizzled source); W bf16.
// BM=BN=128, BK=32, 4 waves. Counted single-barrier double-buffer pipeline.
__global__ __launch_bounds__(256, 3)
void qkv_gemm(const float* __restrict__ Aq, const float* __restrict__ Ak,
              const float* __restrict__ Av,
              const short* __restrict__ Wq, const short* __restrict__ Wk,
              const short* __restrict__ Wv,
              short* __restrict__ Qp, short* __restrict__ Kp, short* __restrict__ Vp)
{
  __shared__ char smem[2*24576];   // per buf: A f32 [128][32] 16KB + W bf16 [128][32] 8KB

  const int id  = blockIdx.x;
  const int swz = (id & 7)*96 + (id >> 3);   // XCD k gets contiguous chunk
  const int z   = swz >> 8;
  const int rr  = swz & 255;
  const int m0  = (rr >> 3) * 128, n0 = (rr & 7) * 128;

  const float* Af = (z == 0) ? Aq : (z == 1) ? Ak : Av;
  const short* Wb = (z == 0) ? Wq : (z == 1) ? Wk : Wv;
  short* Cp       = (z == 0) ? Qp : (z == 1) ? Kp : Vp;

  const int tid = threadIdx.x, lane = tid & 63, w = tid >> 6;
  const int wr = w >> 1, wc = w & 1;
  const int l15 = lane & 15, l4 = lane >> 4;

  f32x4 acc[4][4];
  #pragma unroll
  for (int i = 0; i < 4; ++i)
    #pragma unroll
    for (int j = 0; j < 4; ++j) acc[i][j] = f32x4{0.f,0.f,0.f,0.f};

  auto stage = [&](char* buf, int k0) {
    #pragma unroll
    for (int p = 0; p < 4; ++p) {            // A 16KB: 4 waves x 4 x 1KB
      const int off = (w*4 + p)*1024 + lane*16;
      const int row = off >> 7;
      const int cb  = (off & 127) ^ ((row & 7) << 4);
      gload_lds16(Af + (size_t)(m0 + row)*D_MODEL + k0 + (cb >> 2),
                  buf + (w*4 + p)*1024);
    }
    #pragma unroll
    for (int p = 0; p < 2; ++p) {            // W 8KB: 4 waves x 2 x 1KB
      const int off = (w*2 + p)*1024 + lane*16;
      const int row = off >> 6;
      const int cb  = (off & 63) ^ ((row & 3) << 4);
      gload_lds16(Wb + (size_t)(n0 + row)*D_MODEL + k0 + (cb >> 1),
                  buf + 16384 + (w*2 + p)*1024);
    }
  };

  stage(smem, 0);
  wait_vm0();
  __builtin_amdgcn_s_barrier();

  for (int kt = 0; kt < D_MODEL/32; ++kt) {
    char* buf = smem + (kt & 1)*24576;
    if (kt + 1 < D_MODEL/32) stage(smem + ((kt+1) & 1)*24576, (kt+1)*32);

    char* AsB = buf; char* WsB = buf + 16384;
    short8 af[4], bf[4];
    #pragma unroll
    for (int fi = 0; fi < 4; ++fi) {
      const int row = wr*64 + fi*16 + l15;
      const int s_ = (row & 7) << 4;
      f32x4 x0 = *(const f32x4*)(AsB + row*128 + ((l4*32) ^ s_));
      f32x4 x1 = *(const f32x4*)(AsB + row*128 + ((l4*32 + 16) ^ s_));
      short8 a;
      a[0]=bf16s(x0[0]); a[1]=bf16s(x0[1]); a[2]=bf16s(x0[2]); a[3]=bf16s(x0[3]);
      a[4]=bf16s(x1[0]); a[5]=bf16s(x1[1]); a[6]=bf16s(x1[2]); a[7]=bf16s(x1[3]);
      af[fi] = a;
    }
    #pragma unroll
    for (int fj = 0; fj < 4; ++fj) {
      const int row = wc*64 + fj*16 + l15;
      bf[fj] = *(const short8*)(WsB + row*64 + ((l4*16) ^ ((row & 3) << 4)));
    }
    #pragma unroll
    for (int fi = 0; fi < 4; ++fi)
      #pragma unroll
      for (int fj = 0; fj < 4; ++fj)
        acc[fi][fj] = __builtin_amdgcn_mfma_f32_16x16x32_bf16(af[fi], bf[fj], acc[fi][fj], 0, 0, 0);

    wait_vm0();                     // next-tile stage done (hidden under MFMAs)
    __builtin_amdgcn_s_barrier();
  }

  #pragma unroll
  for (int fi = 0; fi < 4; ++fi)
    #pragma unroll
    for (int fj = 0; fj < 4; ++fj)
      #pragma unroll
      for (int r = 0; r < 4; ++r) {
        const int m = m0 + wr*64 + fi*16 + l4*4 + r;
        const int j = n0 + wc*64 + fj*16 + l15;
        const int b = m >> 11, n = m & (SEQ-1);
        const int h = j >> 6,  d = j & 63;
        const short v = bf16s(acc[fi][fj][r]);
        if (z == 2)
          Cp[((size_t)(b*NH + h)*DH + d)*SEQ + n] = v;          // V^T
        else
          Cp[(((size_t)(b*NH + h)*SEQ + n) << 6) + d] = v;      // per-head
      }
}

// ---------------- output GEMM: d_out = Ao @ Wo^T + bias (bf16 in, f32 out) --
// 1D grid 512, XCD-swizzled. BM=128 BN=64 BK=32, same pipeline.
__global__ __launch_bounds__(256, 4)
void gemm_out(const short* __restrict__ A, const short* __restrict__ Wb,
              const float* __restrict__ bias, float* __restrict__ Cp)
{
  __shared__ char smem[2*12288];   // per buf: A bf16 [128][32] 8KB + W [64][32] 4KB

  const int id  = blockIdx.x;
  const int swz = (id & 7)*64 + (id >> 3);
  const int m0  = (swz >> 4) * 128, n0 = (swz & 15) * 64;

  const int tid = threadIdx.x, lane = tid & 63, w = tid >> 6;
  const int wr = w >> 1, wc = w & 1;
  const int l15 = lane & 15, l4 = lane >> 4;

  f32x4 acc[4][2];
  #pragma unroll
  for (int i = 0; i < 4; ++i)
    #pragma unroll
    for (int j = 0; j < 2; ++j) acc[i][j] = f32x4{0.f,0.f,0.f,0.f};

  auto stage = [&](char* buf, int k0) {
    #pragma unroll
    for (int p = 0; p < 2; ++p) {            // A 8KB
      const int off = (w*2 + p)*1024 + lane*16;
      const int row = off >> 6;
      const int cb  = (off & 63) ^ ((row & 3) << 4);
      gload_lds16(A + (size_t)(m0 + row)*D_MODEL + k0 + (cb >> 1),
                  buf + (w*2 + p)*1024);
    }
    {                                         // W 4KB
      const int off = w*1024 + lane*16;
      const int row = off >> 6;
      const int cb  = (off & 63) ^ ((row & 3) << 4);
      gload_lds16(Wb + (size_t)(n0 + row)*D_MODEL + k0 + (cb >> 1),
                  buf + 8192 + w*1024);
    }
  };

  stage(smem, 0);
  wait_vm0();
  __builtin_amdgcn_s_barrier();

  for (int kt = 0; kt < D_MODEL/32; ++kt) {
    char* buf = smem + (kt & 1)*12288;
    if (kt + 1 < D_MODEL/32) stage(smem + ((kt+1) & 1)*12288, (kt+1)*32);

    char* AsB = buf; char* WsB = buf + 8192;
    short8 af[4], bf[2];
    #pragma unroll
    for (int fi = 0; fi < 4; ++fi) {
      const int row = wr*64 + fi*16 + l15;
      af[fi] = *(const short8*)(AsB + row*64 + ((l4*16) ^ ((row & 3) << 4)));
    }
    #pragma unroll
    for (int fj = 0; fj < 2; ++fj) {
      const int row = wc*32 + fj*16 + l15;
      bf[fj] = *(const short8*)(WsB + row*64 + ((l4*16) ^ ((row & 3) << 4)));
    }
    #pragma unroll
    for (int fi = 0; fi < 4; ++fi)
      #pragma unroll
      for (int fj = 0; fj < 2; ++fj)
        acc[fi][fj] = __builtin_amdgcn_mfma_f32_16x16x32_bf16(af[fi], bf[fj], acc[fi][fj], 0, 0, 0);

    wait_vm0();
    __builtin_amdgcn_s_barrier();
  }

  float bj[2];
  #pragma unroll
  for (int fj = 0; fj < 2; ++fj) bj[fj] = bias[n0 + wc*32 + fj*16 + l15];
  #pragma unroll
  for (int fi = 0; fi < 4; ++fi)
    #pragma unroll
    for (int fj = 0; fj < 2; ++fj)
      #pragma unroll
      for (int r = 0; r < 4; ++r) {
        const int m = m0 + wr*64 + fi*16 + l4*4 + r;
        const int j = n0 + wc*32 + fj*16 + l15;
        Cp[(size_t)m*D_MODEL + j] = acc[fi][fj][r] + bj[fj];
      }
}

// ---------------- Flash attention, swapped QK^T, gload_lds pipeline ---------
// Qh (PRE-SCALED): bf16 [B*H][SEQ][64]; Kh same; Vt: bf16 [B*H][64][SEQ].
// AO: bf16 [B][SEQ][1024]. 8 waves; wave owns 16 q-rows (lane l15 = q-row).
__global__ __launch_bounds__(512, 2)
void attn_fwd(const short* __restrict__ Qh, const short* __restrict__ Kh,
              const short* __restrict__ Vt, __hip_bfloat16* __restrict__ AO)
{
  __shared__ char smem[2*16384 + 16384];   // K/V dbuf (8KB K + 8KB V each) + Ps 16KB
  char* PsAll = smem + 32768;

  const int id  = blockIdx.x;
  const int swz = (id & 7)*64 + (id >> 3);   // consecutive share bh -> same XCD
  const int bh  = swz >> 4;
  const int q0  = (swz & 15) * 128;

  const int tid = threadIdx.x, lane = tid & 63, w = tid >> 6;
  const int l15 = lane & 15, l4 = lane >> 4;
  const int b = bh >> 4, h = bh & 15;
  const size_t base = (size_t)bh * SEQ * DH;
  char* PsB = PsAll + w * 2048;

  const short* Kg = Kh + base;
  const short* Vg = Vt + base;

  short8 qf[2];
  #pragma unroll
  for (int kc = 0; kc < 2; ++kc)
    qf[kc] = *(const short8*)(Qh + base + (size_t)(q0 + w*16 + l15)*DH + kc*32 + l4*8);

  float m = -1e30f, l = 0.f;
  f32x4 o[4];
  #pragma unroll
  for (int fj = 0; fj < 4; ++fj) o[fj] = f32x4{0.f,0.f,0.f,0.f};

  // per-wave staging: wave w stages 1KB of K and 1KB of V, pre-swizzled source
  const int soff = w*1024 + lane*16;
  const int srow = soff >> 7;                     // 128B rows (64 shorts)
  const int scb  = (soff & 127) ^ ((srow & 7) << 4);

  auto stage = [&](char* buf, int kt) {
    gload_lds16(Kg + (size_t)(kt*64 + srow)*DH + (scb >> 1), buf + w*1024);
    gload_lds16(Vg + (size_t)srow*SEQ + kt*64 + (scb >> 1),  buf + 8192 + w*1024);
  };

  stage(smem, 0);
  wait_vm0();
  __builtin_amdgcn_s_barrier();

  constexpr int NT = SEQ/64;
  for (int kt = 0; kt < NT; ++kt) {
    char* KsB = smem + (kt & 1)*16384;
    char* VsB = KsB + 8192;
    if (kt + 1 < NT) stage(smem + ((kt+1) & 1)*16384, kt + 1);

    // S^T = K Q^T : lane holds S[q=l15][kv = fj*16 + l4*4 + r]
    f32x4 s[4];
    #pragma unroll
    for (int fj = 0; fj < 4; ++fj) s[fj] = f32x4{0.f,0.f,0.f,0.f};
    #pragma unroll
    for (int kc = 0; kc < 2; ++kc)
      #pragma unroll
      for (int fj = 0; fj < 4; ++fj) {
        const int row = fj*16 + l15;
        short8 kf = *(const short8*)(KsB + ((row*128 + (kc*32 + l4*8)*2) ^ ((row & 7) << 4)));
        s[fj] = __builtin_amdgcn_mfma_f32_16x16x32_bf16(kf, qf[kc], s[fj], 0, 0, 0);
      }

    // online softmax (exp2 domain, Q pre-scaled)
    float pmax = s[0][0];
    #pragma unroll
    for (int fj = 0; fj < 4; ++fj)
      #pragma unroll
      for (int r = 0; r < 4; ++r) pmax = fmaxf(pmax, s[fj][r]);
    pmax = fmaxf(pmax, __shfl_xor(pmax, 16, 64));
    pmax = fmaxf(pmax, __shfl_xor(pmax, 32, 64));
    const float mn = fmaxf(m, pmax);
    const float al = fast_exp2(m - mn);
    m = mn;
    float rs = 0.f;
    #pragma unroll
    for (int fj = 0; fj < 4; ++fj)
      #pragma unroll
      for (int r = 0; r < 4; ++r) {
        s[fj][r] = fast_exp2(s[fj][r] - m);
        rs += s[fj][r];
      }
    rs += __shfl_xor(rs, 16, 64);
    rs += __shfl_xor(rs, 32, 64);
    l = l * al + rs;

    // P -> per-wave LDS (bf16, swizzled); same-wave ordering, no barrier
    #pragma unroll
    for (int fj = 0; fj < 4; ++fj) {
      short4v c;
      c[0]=bf16s(s[fj][0]); c[1]=bf16s(s[fj][1]); c[2]=bf16s(s[fj][2]); c[3]=bf16s(s[fj][3]);
      const int byo = (l15*128 + (fj*16 + l4*4)*2) ^ ((l15 & 7) << 4);
      *(short4v*)(PsB + byo) = c;
    }

    // rescale O by al
    float alr[4];
    #pragma unroll
    for (int r = 0; r < 4; ++r) alr[r] = __shfl(al, l4*4 + r, 64);
    #pragma unroll
    for (int fj = 0; fj < 4; ++fj)
      #pragma unroll
      for (int r = 0; r < 4; ++r) o[fj][r] *= alr[r];

    // O += P V
    #pragma unroll
    for (int kc = 0; kc < 2; ++kc) {
      const int pb = (l15*128 + (kc*32 + l4*8)*2) ^ ((l15 & 7) << 4);
      short8 pa = *(const short8*)(PsB + pb);
      #pragma unroll
      for (int fj = 0; fj < 4; ++fj) {
        const int row = fj*16 + l15;
        short8 vf = *(const short8*)(VsB + ((row*128 + (kc*32 + l4*8)*2) ^ ((row & 7) << 4)));
        o[fj] = __builtin_amdgcn_mfma_f32_16x16x32_bf16(pa, vf, o[fj], 0, 0, 0);
      }
    }

    wait_vm0();                    // next K/V tile landed (hidden under compute)
    __builtin_amdgcn_s_barrier();
  }

  const float inv = 1.0f / l;
  float ivr[4];
  #pragma unroll
  for (int r = 0; r < 4; ++r) ivr[r] = __shfl(inv, l4*4 + r, 64);
  #pragma unroll
  for (int fj = 0; fj < 4; ++fj)
    #pragma unroll
    for (int r = 0; r < 4; ++r) {
      const int n = q0 + w*16 + l4*4 + r;
      const int d = h*64 + fj*16 + l15;
      AO[(size_t)(b*SEQ + n)*D_MODEL + d] = __float2bfloat16(o[fj][r] * ivr[r]);
    }
}

extern "C" void kernel_launch(void* const* d_in, const int* in_sizes, int n_in,
                              void* d_out, int out_size, void* d_ws, size_t ws_size,
                              hipStream_t stream)
{
  const float* query = (const float*)d_in[0];
  const float* key_  = (const float*)d_in[1];
  const float* value = (const float*)d_in[2];
  const float* Wq = (const float*)d_in[3];
  const float* Wk = (const float*)d_in[4];
  const float* Wv = (const float*)d_in[5];
  const float* Wo = (const float*)d_in[6];
  const float* bo = (const float*)d_in[7];

  // 32 MiB total:
  // [0,8M): Qp -> Wob (after attn)   [8,16M): Kp   [16,24M): Vp
  // [24,32M): Wqb/Wkb/Wvb -> Ao (after projections)
  char* wsb = (char*)d_ws;
  short* Qp  = (short*)(wsb);
  short* Kp  = (short*)(wsb + (8u  << 20));
  short* Vp  = (short*)(wsb + (16u << 20));
  short* Wqb = (short*)(wsb + (24u << 20));
  short* Wkb = (short*)(wsb + (26u << 20));
  short* Wvb = (short*)(wsb + (28u << 20));
  short* Ao  = (short*)(wsb + (24u << 20));
  short* Wob = (short*)(wsb);

  const int nW = D_MODEL*D_MODEL/8;
  castk<<<nW/256, 256, 0, stream>>>(Wq, Wqb, nW, SCALE_LOG2E);
  castk<<<nW/256, 256, 0, stream>>>(Wk, Wkb, nW, 1.f);
  castk<<<nW/256, 256, 0, stream>>>(Wv, Wvb, nW, 1.f);

  qkv_gemm<<<768, 256, 0, stream>>>(query, key_, value, Wqb, Wkb, Wvb, Qp, Kp, Vp);
  attn_fwd<<<512, 512, 0, stream>>>(Qp, Kp, Vp, (__hip_bfloat16*)Ao);

  castk<<<nW/256, 256, 0, stream>>>(Wo, Wob, nW, 1.f);
  gemm_out<<<512, 256, 0, stream>>>(Ao, Wob, bo, (float*)d_out);
}

// Round 7
// 238.310 us; speedup vs baseline: 1.6259x; 1.0185x over previous
//
#include <hip/hip_runtime.h>
#include <hip/hip_bf16.h>

typedef __attribute__((ext_vector_type(8))) short short8;
typedef __attribute__((ext_vector_type(4))) short short4v;
typedef __attribute__((ext_vector_type(4))) float f32x4;

#define DEVFN static __device__ __forceinline__

constexpr int D_MODEL = 1024;
constexpr int NH  = 16;
constexpr int DH  = 64;
constexpr int SEQ = 2048;
constexpr float SCALE_LOG2E = 0.125f * 1.44269504088896341f;

DEVFN short bf16s(float f) {
  __hip_bfloat16 h = __float2bfloat16(f);
  short s; __builtin_memcpy(&s, &h, 2);
  return s;
}

DEVFN float fast_exp2(float x) {
#if __has_builtin(__builtin_amdgcn_exp2f)
  return __builtin_amdgcn_exp2f(x);
#else
  return exp2f(x);
#endif
}

DEVFN int inc3(int x) { return x == 2 ? 0 : x + 1; }

// async global->LDS, 16B per lane. LDS dest is wave-uniform base + lane*16.
DEVFN void gload_lds16(const void* g, void* l) {
  __builtin_amdgcn_global_load_lds(
      (const __attribute__((address_space(1))) unsigned int*)g,
      (__attribute__((address_space(3))) unsigned int*)l, 16, 0, 0);
}

// ---------------- cast f32 -> bf16 (optionally scaled), 8 elems/thread ------
__global__ __launch_bounds__(256)
void castk(const float* __restrict__ src, short* __restrict__ dst, int n8, float scale)
{
  int i = blockIdx.x * blockDim.x + threadIdx.x;
  if (i >= n8) return;
  const float4 a = *(const float4*)(src + (size_t)i*8);
  const float4 b = *(const float4*)(src + (size_t)i*8 + 4);
  short8 v;
  v[0]=bf16s(a.x*scale); v[1]=bf16s(a.y*scale); v[2]=bf16s(a.z*scale); v[3]=bf16s(a.w*scale);
  v[4]=bf16s(b.x*scale); v[5]=bf16s(b.y*scale); v[6]=bf16s(b.z*scale); v[7]=bf16s(b.w*scale);
  *(short8*)(dst + (size_t)i*8) = v;
}

// ---------------- fused QKV projection ---------------------------------------
// 1D grid 768, XCD-swizzled. z=0:Q z=1:K (per-head [B,H,S,DH]); z=2:V^T.
// A f32 via global_load_lds (pre-swizzled source); W bf16.
// BM=BN=128, BK=32. 3-buffer counted-vmcnt pipeline (depth 2, L=6).
__global__ __launch_bounds__(256, 2)
void qkv_gemm(const float* __restrict__ Aq, const float* __restrict__ Ak,
              const float* __restrict__ Av,
              const short* __restrict__ Wq, const short* __restrict__ Wk,
              const short* __restrict__ Wv,
              short* __restrict__ Qp, short* __restrict__ Kp, short* __restrict__ Vp)
{
  __shared__ char smem[3*24576];   // per buf: A f32 [128][32] 16KB + W bf16 [128][32] 8KB

  const int id  = blockIdx.x;
  const int swz = (id & 7)*96 + (id >> 3);   // XCD k gets contiguous chunk
  const int z   = swz >> 8;
  const int rr  = swz & 255;
  const int m0  = (rr >> 3) * 128, n0 = (rr & 7) * 128;

  const float* Af = (z == 0) ? Aq : (z == 1) ? Ak : Av;
  const short* Wb = (z == 0) ? Wq : (z == 1) ? Wk : Wv;
  short* Cp       = (z == 0) ? Qp : (z == 1) ? Kp : Vp;

  const int tid = threadIdx.x, lane = tid & 63, w = tid >> 6;
  const int wr = w >> 1, wc = w & 1;
  const int l15 = lane & 15, l4 = lane >> 4;

  f32x4 acc[4][4];
  #pragma unroll
  for (int i = 0; i < 4; ++i)
    #pragma unroll
    for (int j = 0; j < 4; ++j) acc[i][j] = f32x4{0.f,0.f,0.f,0.f};

  auto stage = [&](int sb, int k0) {
    char* buf = smem + sb*24576;
    #pragma unroll
    for (int p = 0; p < 4; ++p) {            // A 16KB: 4 waves x 4 x 1KB
      const int off = (w*4 + p)*1024 + lane*16;
      const int row = off >> 7;
      const int cb  = (off & 127) ^ ((row & 7) << 4);
      gload_lds16(Af + (size_t)(m0 + row)*D_MODEL + k0 + (cb >> 2),
                  buf + (w*4 + p)*1024);
    }
    #pragma unroll
    for (int p = 0; p < 2; ++p) {            // W 8KB: 4 waves x 2 x 1KB
      const int off = (w*2 + p)*1024 + lane*16;
      const int row = off >> 6;
      const int cb  = (off & 63) ^ ((row & 3) << 4);
      gload_lds16(Wb + (size_t)(n0 + row)*D_MODEL + k0 + (cb >> 1),
                  buf + 16384 + (w*2 + p)*1024);
    }
  };

  auto compute = [&](int cb_) {
    char* AsB = smem + cb_*24576;
    char* WsB = AsB + 16384;
    short8 af[4], bf[4];
    #pragma unroll
    for (int fi = 0; fi < 4; ++fi) {
      const int row = wr*64 + fi*16 + l15;
      const int s_ = (row & 7) << 4;
      f32x4 x0 = *(const f32x4*)(AsB + row*128 + ((l4*32) ^ s_));
      f32x4 x1 = *(const f32x4*)(AsB + row*128 + ((l4*32 + 16) ^ s_));
      short8 a;
      a[0]=bf16s(x0[0]); a[1]=bf16s(x0[1]); a[2]=bf16s(x0[2]); a[3]=bf16s(x0[3]);
      a[4]=bf16s(x1[0]); a[5]=bf16s(x1[1]); a[6]=bf16s(x1[2]); a[7]=bf16s(x1[3]);
      af[fi] = a;
    }
    #pragma unroll
    for (int fj = 0; fj < 4; ++fj) {
      const int row = wc*64 + fj*16 + l15;
      bf[fj] = *(const short8*)(WsB + row*64 + ((l4*16) ^ ((row & 3) << 4)));
    }
    #pragma unroll
    for (int fi = 0; fi < 4; ++fi)
      #pragma unroll
      for (int fj = 0; fj < 4; ++fj)
        acc[fi][fj] = __builtin_amdgcn_mfma_f32_16x16x32_bf16(af[fi], bf[fj], acc[fi][fj], 0, 0, 0);
  };

  constexpr int NIT = D_MODEL/32;
  stage(0, 0);
  stage(1, 32);
  int cur = 0, nxt = 2;
  for (int kt = 0; kt < NIT-1; ++kt) {
    asm volatile("s_waitcnt vmcnt(6)" ::: "memory");   // tile kt landed; kt+1 in flight
    __builtin_amdgcn_s_barrier();
    __builtin_amdgcn_sched_barrier(0);
    if (kt + 2 < NIT) stage(nxt, (kt+2)*32);
    compute(cur);
    cur = inc3(cur); nxt = inc3(nxt);
  }
  asm volatile("s_waitcnt vmcnt(0)" ::: "memory");
  __builtin_amdgcn_s_barrier();
  __builtin_amdgcn_sched_barrier(0);
  compute(cur);

  #pragma unroll
  for (int fi = 0; fi < 4; ++fi)
    #pragma unroll
    for (int fj = 0; fj < 4; ++fj)
      #pragma unroll
      for (int r = 0; r < 4; ++r) {
        const int m = m0 + wr*64 + fi*16 + l4*4 + r;
        const int j = n0 + wc*64 + fj*16 + l15;
        const int b = m >> 11, n = m & (SEQ-1);
        const int h = j >> 6,  d = j & 63;
        const short v = bf16s(acc[fi][fj][r]);
        if (z == 2)
          Cp[((size_t)(b*NH + h)*DH + d)*SEQ + n] = v;          // V^T
        else
          Cp[(((size_t)(b*NH + h)*SEQ + n) << 6) + d] = v;      // per-head
      }
}

// ---------------- output GEMM: d_out = Ao @ Wo^T + bias (bf16 in, f32 out) --
// 1D grid 512, XCD-swizzled. BM=128 BN=64 BK=32. 3-buf pipeline, L=3.
__global__ __launch_bounds__(256, 4)
void gemm_out(const short* __restrict__ A, const short* __restrict__ Wb,
              const float* __restrict__ bias, float* __restrict__ Cp)
{
  __shared__ char smem[3*12288];   // per buf: A bf16 [128][32] 8KB + W [64][32] 4KB

  const int id  = blockIdx.x;
  const int swz = (id & 7)*64 + (id >> 3);
  const int m0  = (swz >> 4) * 128, n0 = (swz & 15) * 64;

  const int tid = threadIdx.x, lane = tid & 63, w = tid >> 6;
  const int wr = w >> 1, wc = w & 1;
  const int l15 = lane & 15, l4 = lane >> 4;

  f32x4 acc[4][2];
  #pragma unroll
  for (int i = 0; i < 4; ++i)
    #pragma unroll
    for (int j = 0; j < 2; ++j) acc[i][j] = f32x4{0.f,0.f,0.f,0.f};

  auto stage = [&](int sb, int k0) {
    char* buf = smem + sb*12288;
    #pragma unroll
    for (int p = 0; p < 2; ++p) {            // A 8KB
      const int off = (w*2 + p)*1024 + lane*16;
      const int row = off >> 6;
      const int cb  = (off & 63) ^ ((row & 3) << 4);
      gload_lds16(A + (size_t)(m0 + row)*D_MODEL + k0 + (cb >> 1),
                  buf + (w*2 + p)*1024);
    }
    {                                         // W 4KB
      const int off = w*1024 + lane*16;
      const int row = off >> 6;
      const int cb  = (off & 63) ^ ((row & 3) << 4);
      gload_lds16(Wb + (size_t)(n0 + row)*D_MODEL + k0 + (cb >> 1),
                  buf + 8192 + w*1024);
    }
  };

  auto compute = [&](int cb_) {
    char* AsB = smem + cb_*12288;
    char* WsB = AsB + 8192;
    short8 af[4], bf[2];
    #pragma unroll
    for (int fi = 0; fi < 4; ++fi) {
      const int row = wr*64 + fi*16 + l15;
      af[fi] = *(const short8*)(AsB + row*64 + ((l4*16) ^ ((row & 3) << 4)));
    }
    #pragma unroll
    for (int fj = 0; fj < 2; ++fj) {
      const int row = wc*32 + fj*16 + l15;
      bf[fj] = *(const short8*)(WsB + row*64 + ((l4*16) ^ ((row & 3) << 4)));
    }
    #pragma unroll
    for (int fi = 0; fi < 4; ++fi)
      #pragma unroll
      for (int fj = 0; fj < 2; ++fj)
        acc[fi][fj] = __builtin_amdgcn_mfma_f32_16x16x32_bf16(af[fi], bf[fj], acc[fi][fj], 0, 0, 0);
  };

  constexpr int NIT = D_MODEL/32;
  stage(0, 0);
  stage(1, 32);
  int cur = 0, nxt = 2;
  for (int kt = 0; kt < NIT-1; ++kt) {
    asm volatile("s_waitcnt vmcnt(3)" ::: "memory");
    __builtin_amdgcn_s_barrier();
    __builtin_amdgcn_sched_barrier(0);
    if (kt + 2 < NIT) stage(nxt, (kt+2)*32);
    compute(cur);
    cur = inc3(cur); nxt = inc3(nxt);
  }
  asm volatile("s_waitcnt vmcnt(0)" ::: "memory");
  __builtin_amdgcn_s_barrier();
  __builtin_amdgcn_sched_barrier(0);
  compute(cur);

  float bj[2];
  #pragma unroll
  for (int fj = 0; fj < 2; ++fj) bj[fj] = bias[n0 + wc*32 + fj*16 + l15];
  #pragma unroll
  for (int fi = 0; fi < 4; ++fi)
    #pragma unroll
    for (int fj = 0; fj < 2; ++fj)
      #pragma unroll
      for (int r = 0; r < 4; ++r) {
        const int m = m0 + wr*64 + fi*16 + l4*4 + r;
        const int j = n0 + wc*32 + fj*16 + l15;
        Cp[(size_t)m*D_MODEL + j] = acc[fi][fj][r] + bj[fj];
      }
}

// ---------------- Flash attention, swapped QK^T, counted pipeline -----------
// Qh (PRE-SCALED): bf16 [B*H][SEQ][64]; Kh same; Vt: bf16 [B*H][64][SEQ].
// AO: bf16 [B][SEQ][1024]. 8 waves; wave owns 16 q-rows (lane l15 = q-row).
// 3-buffer K/V pipeline (L=2), exact skip-rescale.
__global__ __launch_bounds__(512, 4)
void attn_fwd(const short* __restrict__ Qh, const short* __restrict__ Kh,
              const short* __restrict__ Vt, __hip_bfloat16* __restrict__ AO)
{
  __shared__ char smem[3*16384 + 16384];   // 3 x (8KB K + 8KB V) + Ps 16KB
  char* PsAll = smem + 49152;

  const int id  = blockIdx.x;
  const int swz = (id & 7)*64 + (id >> 3);   // consecutive share bh -> same XCD
  const int bh  = swz >> 4;
  const int q0  = (swz & 15) * 128;

  const int tid = threadIdx.x, lane = tid & 63, w = tid >> 6;
  const int l15 = lane & 15, l4 = lane >> 4;
  const int b = bh >> 4, h = bh & 15;
  const size_t base = (size_t)bh * SEQ * DH;
  char* PsB = PsAll + w * 2048;

  const short* Kg = Kh + base;
  const short* Vg = Vt + base;

  short8 qf[2];
  #pragma unroll
  for (int kc = 0; kc < 2; ++kc)
    qf[kc] = *(const short8*)(Qh + base + (size_t)(q0 + w*16 + l15)*DH + kc*32 + l4*8);

  float m = -1e30f, l = 0.f;
  f32x4 o[4];
  #pragma unroll
  for (int fj = 0; fj < 4; ++fj) o[fj] = f32x4{0.f,0.f,0.f,0.f};

  // per-wave staging: wave w stages 1KB of K and 1KB of V, pre-swizzled source
  const int soff = w*1024 + lane*16;
  const int srow = soff >> 7;                     // 128B rows (64 shorts)
  const int scb  = (soff & 127) ^ ((srow & 7) << 4);

  auto stage = [&](int sb, int kt) {
    char* buf = smem + sb*16384;
    gload_lds16(Kg + (size_t)(kt*64 + srow)*DH + (scb >> 1), buf + w*1024);
    gload_lds16(Vg + (size_t)srow*SEQ + kt*64 + (scb >> 1),  buf + 8192 + w*1024);
  };

  auto compute = [&](int cb_) {
    char* KsB = smem + cb_*16384;
    char* VsB = KsB + 8192;

    // S^T = K Q^T : lane holds S[q=l15][kv = fj*16 + l4*4 + r]
    f32x4 s[4];
    #pragma unroll
    for (int fj = 0; fj < 4; ++fj) s[fj] = f32x4{0.f,0.f,0.f,0.f};
    #pragma unroll
    for (int kc = 0; kc < 2; ++kc)
      #pragma unroll
      for (int fj = 0; fj < 4; ++fj) {
        const int row = fj*16 + l15;
        short8 kf = *(const short8*)(KsB + ((row*128 + (kc*32 + l4*8)*2) ^ ((row & 7) << 4)));
        s[fj] = __builtin_amdgcn_mfma_f32_16x16x32_bf16(kf, qf[kc], s[fj], 0, 0, 0);
      }

    // online softmax (exp2 domain, Q pre-scaled)
    float pmax = s[0][0];
    #pragma unroll
    for (int fj = 0; fj < 4; ++fj)
      #pragma unroll
      for (int r = 0; r < 4; ++r) pmax = fmaxf(pmax, s[fj][r]);
    pmax = fmaxf(pmax, __shfl_xor(pmax, 16, 64));
    pmax = fmaxf(pmax, __shfl_xor(pmax, 32, 64));

    if (!__all(pmax <= m)) {          // exact: when pmax<=m everywhere, al==1
      const float mn = fmaxf(m, pmax);
      const float al = fast_exp2(m - mn);
      m = mn;
      l *= al;
      float alr[4];
      #pragma unroll
      for (int r = 0; r < 4; ++r) alr[r] = __shfl(al, l4*4 + r, 64);
      #pragma unroll
      for (int fj = 0; fj < 4; ++fj)
        #pragma unroll
        for (int r = 0; r < 4; ++r) o[fj][r] *= alr[r];
    }

    float rs = 0.f;
    #pragma unroll
    for (int fj = 0; fj < 4; ++fj)
      #pragma unroll
      for (int r = 0; r < 4; ++r) {
        s[fj][r] = fast_exp2(s[fj][r] - m);
        rs += s[fj][r];
      }
    rs += __shfl_xor(rs, 16, 64);
    rs += __shfl_xor(rs, 32, 64);
    l += rs;

    // P -> per-wave LDS (bf16, swizzled); same-wave ordering, no barrier
    #pragma unroll
    for (int fj = 0; fj < 4; ++fj) {
      short4v c;
      c[0]=bf16s(s[fj][0]); c[1]=bf16s(s[fj][1]); c[2]=bf16s(s[fj][2]); c[3]=bf16s(s[fj][3]);
      const int byo = (l15*128 + (fj*16 + l4*4)*2) ^ ((l15 & 7) << 4);
      *(short4v*)(PsB + byo) = c;
    }

    // O += P V
    #pragma unroll
    for (int kc = 0; kc < 2; ++kc) {
      const int pb = (l15*128 + (kc*32 + l4*8)*2) ^ ((l15 & 7) << 4);
      short8 pa = *(const short8*)(PsB + pb);
      #pragma unroll
      for (int fj = 0; fj < 4; ++fj) {
        const int row = fj*16 + l15;
        short8 vf = *(const short8*)(VsB + ((row*128 + (kc*32 + l4*8)*2) ^ ((row & 7) << 4)));
        o[fj] = __builtin_amdgcn_mfma_f32_16x16x32_bf16(pa, vf, o[fj], 0, 0, 0);
      }
    }
  };

  constexpr int NT = SEQ/64;
  stage(0, 0);
  stage(1, 1);
  int cur = 0, nxt = 2;
  for (int kt = 0; kt < NT-1; ++kt) {
    asm volatile("s_waitcnt vmcnt(2)" ::: "memory");   // tile kt landed; kt+1 in flight
    __builtin_amdgcn_s_barrier();
    __builtin_amdgcn_sched_barrier(0);
    if (kt + 2 < NT) stage(nxt, kt + 2);
    compute(cur);
    cur = inc3(cur); nxt = inc3(nxt);
  }
  asm volatile("s_waitcnt vmcnt(0)" ::: "memory");
  __builtin_amdgcn_s_barrier();
  __builtin_amdgcn_sched_barrier(0);
  compute(cur);

  const float inv = 1.0f / l;
  float ivr[4];
  #pragma unroll
  for (int r = 0; r < 4; ++r) ivr[r] = __shfl(inv, l4*4 + r, 64);
  #pragma unroll
  for (int fj = 0; fj < 4; ++fj)
    #pragma unroll
    for (int r = 0; r < 4; ++r) {
      const int n = q0 + w*16 + l4*4 + r;
      const int d = h*64 + fj*16 + l15;
      AO[(size_t)(b*SEQ + n)*D_MODEL + d] = __float2bfloat16(o[fj][r] * ivr[r]);
    }
}

extern "C" void kernel_launch(void* const* d_in, const int* in_sizes, int n_in,
                              void* d_out, int out_size, void* d_ws, size_t ws_size,
                              hipStream_t stream)
{
  const float* query = (const float*)d_in[0];
  const float* key_  = (const float*)d_in[1];
  const float* value = (const float*)d_in[2];
  const float* Wq = (const float*)d_in[3];
  const float* Wk = (const float*)d_in[4];
  const float* Wv = (const float*)d_in[5];
  const float* Wo = (const float*)d_in[6];
  const float* bo = (const float*)d_in[7];

  // 32 MiB total:
  // [0,8M): Qp -> Wob (after attn)   [8,16M): Kp   [16,24M): Vp
  // [24,32M): Wqb/Wkb/Wvb -> Ao (after projections)
  char* wsb = (char*)d_ws;
  short* Qp  = (short*)(wsb);
  short* Kp  = (short*)(wsb + (8u  << 20));
  short* Vp  = (short*)(wsb + (16u << 20));
  short* Wqb = (short*)(wsb + (24u << 20));
  short* Wkb = (short*)(wsb + (26u << 20));
  short* Wvb = (short*)(wsb + (28u << 20));
  short* Ao  = (short*)(wsb + (24u << 20));
  short* Wob = (short*)(wsb);

  const int nW = D_MODEL*D_MODEL/8;
  castk<<<nW/256, 256, 0, stream>>>(Wq, Wqb, nW, SCALE_LOG2E);
  castk<<<nW/256, 256, 0, stream>>>(Wk, Wkb, nW, 1.f);
  castk<<<nW/256, 256, 0, stream>>>(Wv, Wvb, nW, 1.f);

  qkv_gemm<<<768, 256, 0, stream>>>(query, key_, value, Wqb, Wkb, Wvb, Qp, Kp, Vp);
  attn_fwd<<<512, 512, 0, stream>>>(Qp, Kp, Vp, (__hip_bfloat16*)Ao);

  castk<<<nW/256, 256, 0, stream>>>(Wo, Wob, nW, 1.f);
  gemm_out<<<512, 256, 0, stream>>>(Ao, Wob, bo, (float*)d_out);
}

// Round 8
// 237.346 us; speedup vs baseline: 1.6325x; 1.0041x over previous
//
#include <hip/hip_runtime.h>
#include <hip/hip_bf16.h>

typedef __attribute__((ext_vector_type(8))) short short8;
typedef __attribute__((ext_vector_type(4))) short short4v;
typedef __attribute__((ext_vector_type(4))) float f32x4;

#define DEVFN static __device__ __forceinline__

constexpr int D_MODEL = 1024;
constexpr int NH  = 16;
constexpr int DH  = 64;
constexpr int SEQ = 2048;
constexpr float SCALE_LOG2E = 0.125f * 1.44269504088896341f;

DEVFN short bf16s(float f) {
  __hip_bfloat16 h = __float2bfloat16(f);
  short s; __builtin_memcpy(&s, &h, 2);
  return s;
}

DEVFN float fast_exp2(float x) {
#if __has_builtin(__builtin_amdgcn_exp2f)
  return __builtin_amdgcn_exp2f(x);
#else
  return exp2f(x);
#endif
}

DEVFN int inc3(int x) { return x == 2 ? 0 : x + 1; }

// async global->LDS, 16B per lane. LDS dest is wave-uniform base + lane*16.
DEVFN void gload_lds16(const void* g, void* l) {
  __builtin_amdgcn_global_load_lds(
      (const __attribute__((address_space(1))) unsigned int*)g,
      (__attribute__((address_space(3))) unsigned int*)l, 16, 0, 0);
}

// ---------------- cast f32 -> bf16 (optionally scaled), 8 elems/thread ------
__global__ __launch_bounds__(256)
void castk(const float* __restrict__ src, short* __restrict__ dst, int n8, float scale)
{
  int i = blockIdx.x * blockDim.x + threadIdx.x;
  if (i >= n8) return;
  const float4 a = *(const float4*)(src + (size_t)i*8);
  const float4 b = *(const float4*)(src + (size_t)i*8 + 4);
  short8 v;
  v[0]=bf16s(a.x*scale); v[1]=bf16s(a.y*scale); v[2]=bf16s(a.z*scale); v[3]=bf16s(a.w*scale);
  v[4]=bf16s(b.x*scale); v[5]=bf16s(b.y*scale); v[6]=bf16s(b.z*scale); v[7]=bf16s(b.w*scale);
  *(short8*)(dst + (size_t)i*8) = v;
}

// ---------------- bf16 GEMM, m97 shape: BM=BN=128, BK=64, 4 waves -----------
// MODE 0: A linear [4096][1024], C -> bf16 per-head [B,H,S,64]   (Q, K)
// MODE 1: A linear,              C -> bf16 V^T      [B,H,64,S]
// MODE 2: A per-head [B,H,S,64] (K-step kt == head), C -> f32 [4096][1024]+bias
// 3-buffer counted-vmcnt pipeline (depth 2, 8 loads/stage/wave).
template<int MODE>
__global__ __launch_bounds__(256, 1)
void gemm_bf(const short* __restrict__ A, const short* __restrict__ W,
             const float* __restrict__ bias, void* __restrict__ Cp)
{
  __shared__ char smem[3*32768];   // per buf: A [128][64]bf16 16KB + W 16KB

  const int id  = blockIdx.x;
  const int swz = (id & 7)*32 + (id >> 3);   // 256 blocks, XCD-chunked
  const int m0  = (swz >> 3) * 128, n0 = (swz & 7) * 128;

  const int tid = threadIdx.x, lane = tid & 63, w = tid >> 6;
  const int wr = w >> 1, wc = w & 1;
  const int l15 = lane & 15, l4 = lane >> 4;

  f32x4 acc[4][4];
  #pragma unroll
  for (int i = 0; i < 4; ++i)
    #pragma unroll
    for (int j = 0; j < 4; ++j) acc[i][j] = f32x4{0.f,0.f,0.f,0.f};

  auto stage = [&](int sb, int kt) {
    char* buf = smem + sb*32768;
    #pragma unroll
    for (int p = 0; p < 4; ++p) {            // A 16KB: 4 waves x 4 x 1KB
      const int off = (w*4 + p)*1024 + lane*16;
      const int row = off >> 7;              // 128B rows (64 bf16)
      const int cb  = (off & 127) ^ ((row & 7) << 4);
      const short* src;
      if (MODE == 2) {
        const int m = m0 + row;
        const int bb = m >> 11, ss = m & (SEQ-1);
        src = A + (((size_t)(bb*NH + kt)*SEQ + ss) << 6) + (cb >> 1);
      } else {
        src = A + (size_t)(m0 + row)*D_MODEL + kt*64 + (cb >> 1);
      }
      gload_lds16(src, buf + (w*4 + p)*1024);
    }
    #pragma unroll
    for (int p = 0; p < 4; ++p) {            // W 16KB
      const int off = (w*4 + p)*1024 + lane*16;
      const int row = off >> 7;
      const int cb  = (off & 127) ^ ((row & 7) << 4);
      gload_lds16(W + (size_t)(n0 + row)*D_MODEL + kt*64 + (cb >> 1),
                  buf + 16384 + (w*4 + p)*1024);
    }
  };

  auto compute = [&](int cb_) {
    char* AsB = smem + cb_*32768;
    char* WsB = AsB + 16384;
    #pragma unroll
    for (int kc = 0; kc < 2; ++kc) {
      short8 af[4], bf[4];
      #pragma unroll
      for (int fi = 0; fi < 4; ++fi) {
        const int row = wr*64 + fi*16 + l15;
        af[fi] = *(const short8*)(AsB + row*128 + ((kc*64 + l4*16) ^ ((row & 7) << 4)));
      }
      #pragma unroll
      for (int fj = 0; fj < 4; ++fj) {
        const int row = wc*64 + fj*16 + l15;
        bf[fj] = *(const short8*)(WsB + row*128 + ((kc*64 + l4*16) ^ ((row & 7) << 4)));
      }
      #pragma unroll
      for (int fi = 0; fi < 4; ++fi)
        #pragma unroll
        for (int fj = 0; fj < 4; ++fj)
          acc[fi][fj] = __builtin_amdgcn_mfma_f32_16x16x32_bf16(af[fi], bf[fj], acc[fi][fj], 0, 0, 0);
    }
  };

  constexpr int NIT = D_MODEL/64;            // 16 K-steps
  stage(0, 0);
  stage(1, 1);
  int cur = 0, nxt = 2;
  for (int kt = 0; kt < NIT-1; ++kt) {
    asm volatile("s_waitcnt vmcnt(8)" ::: "memory");  // tile kt landed; kt+1 in flight
    __builtin_amdgcn_s_barrier();
    __builtin_amdgcn_sched_barrier(0);
    if (kt + 2 < NIT) stage(nxt, kt + 2);
    compute(cur);
    cur = inc3(cur); nxt = inc3(nxt);
  }
  asm volatile("s_waitcnt vmcnt(0)" ::: "memory");
  __builtin_amdgcn_s_barrier();
  __builtin_amdgcn_sched_barrier(0);
  compute(cur);

  if (MODE == 2) {
    float bj[4];
    #pragma unroll
    for (int fj = 0; fj < 4; ++fj) bj[fj] = bias[n0 + wc*64 + fj*16 + l15];
    #pragma unroll
    for (int fi = 0; fi < 4; ++fi)
      #pragma unroll
      for (int fj = 0; fj < 4; ++fj)
        #pragma unroll
        for (int r = 0; r < 4; ++r) {
          const int m = m0 + wr*64 + fi*16 + l4*4 + r;
          const int j = n0 + wc*64 + fj*16 + l15;
          ((float*)Cp)[(size_t)m*D_MODEL + j] = acc[fi][fj][r] + bj[fj];
        }
  } else {
    #pragma unroll
    for (int fi = 0; fi < 4; ++fi)
      #pragma unroll
      for (int fj = 0; fj < 4; ++fj)
        #pragma unroll
        for (int r = 0; r < 4; ++r) {
          const int m = m0 + wr*64 + fi*16 + l4*4 + r;
          const int j = n0 + wc*64 + fj*16 + l15;
          const int b = m >> 11, n = m & (SEQ-1);
          const int h = j >> 6,  d = j & 63;
          const short v = bf16s(acc[fi][fj][r]);
          if (MODE == 1)
            ((short*)Cp)[((size_t)(b*NH + h)*DH + d)*SEQ + n] = v;      // V^T
          else
            ((short*)Cp)[(((size_t)(b*NH + h)*SEQ + n) << 6) + d] = v;  // per-head
        }
  }
}

// ---------------- Flash attention, swapped QK^T, counted pipeline -----------
// Qh (PRE-SCALED): bf16 [B*H][SEQ][64]; Kh same; Vt: bf16 [B*H][64][SEQ].
// AO: bf16 per-head [B,H,S,64], ALIASES Qh (each block overwrites only the
// Q-rows it loaded into registers at kernel start — self-overwrite safe).
__global__ __launch_bounds__(512, 4)
void attn_fwd(const short* __restrict__ Qh, const short* __restrict__ Kh,
              const short* __restrict__ Vt, short* __restrict__ AO)
{
  __shared__ char smem[3*16384 + 16384];   // 3 x (8KB K + 8KB V) + Ps 16KB
  char* PsAll = smem + 49152;

  const int id  = blockIdx.x;
  const int swz = (id & 7)*64 + (id >> 3);   // consecutive share bh -> same XCD
  const int bh  = swz >> 4;
  const int q0  = (swz & 15) * 128;

  const int tid = threadIdx.x, lane = tid & 63, w = tid >> 6;
  const int l15 = lane & 15, l4 = lane >> 4;
  const int b = bh >> 4, h = bh & 15;
  const size_t base = (size_t)bh * SEQ * DH;
  char* PsB = PsAll + w * 2048;

  const short* Kg = Kh + base;
  const short* Vg = Vt + base;

  short8 qf[2];
  #pragma unroll
  for (int kc = 0; kc < 2; ++kc)
    qf[kc] = *(const short8*)(Qh + base + (size_t)(q0 + w*16 + l15)*DH + kc*32 + l4*8);

  float m = -1e30f, l = 0.f;
  f32x4 o[4];
  #pragma unroll
  for (int fj = 0; fj < 4; ++fj) o[fj] = f32x4{0.f,0.f,0.f,0.f};

  const int soff = w*1024 + lane*16;
  const int srow = soff >> 7;
  const int scb  = (soff & 127) ^ ((srow & 7) << 4);

  auto stage = [&](int sb, int kt) {
    char* buf = smem + sb*16384;
    gload_lds16(Kg + (size_t)(kt*64 + srow)*DH + (scb >> 1), buf + w*1024);
    gload_lds16(Vg + (size_t)srow*SEQ + kt*64 + (scb >> 1),  buf + 8192 + w*1024);
  };

  auto compute = [&](int cb_) {
    char* KsB = smem + cb_*16384;
    char* VsB = KsB + 8192;

    f32x4 s[4];
    #pragma unroll
    for (int fj = 0; fj < 4; ++fj) s[fj] = f32x4{0.f,0.f,0.f,0.f};
    #pragma unroll
    for (int kc = 0; kc < 2; ++kc)
      #pragma unroll
      for (int fj = 0; fj < 4; ++fj) {
        const int row = fj*16 + l15;
        short8 kf = *(const short8*)(KsB + ((row*128 + (kc*32 + l4*8)*2) ^ ((row & 7) << 4)));
        s[fj] = __builtin_amdgcn_mfma_f32_16x16x32_bf16(kf, qf[kc], s[fj], 0, 0, 0);
      }

    float pmax = s[0][0];
    #pragma unroll
    for (int fj = 0; fj < 4; ++fj)
      #pragma unroll
      for (int r = 0; r < 4; ++r) pmax = fmaxf(pmax, s[fj][r]);
    pmax = fmaxf(pmax, __shfl_xor(pmax, 16, 64));
    pmax = fmaxf(pmax, __shfl_xor(pmax, 32, 64));

    if (!__all(pmax <= m)) {          // exact: when pmax<=m everywhere, al==1
      const float mn = fmaxf(m, pmax);
      const float al = fast_exp2(m - mn);
      m = mn;
      l *= al;
      float alr[4];
      #pragma unroll
      for (int r = 0; r < 4; ++r) alr[r] = __shfl(al, l4*4 + r, 64);
      #pragma unroll
      for (int fj = 0; fj < 4; ++fj)
        #pragma unroll
        for (int r = 0; r < 4; ++r) o[fj][r] *= alr[r];
    }

    float rs = 0.f;
    #pragma unroll
    for (int fj = 0; fj < 4; ++fj)
      #pragma unroll
      for (int r = 0; r < 4; ++r) {
        s[fj][r] = fast_exp2(s[fj][r] - m);
        rs += s[fj][r];
      }
    rs += __shfl_xor(rs, 16, 64);
    rs += __shfl_xor(rs, 32, 64);
    l += rs;

    #pragma unroll
    for (int fj = 0; fj < 4; ++fj) {
      short4v c;
      c[0]=bf16s(s[fj][0]); c[1]=bf16s(s[fj][1]); c[2]=bf16s(s[fj][2]); c[3]=bf16s(s[fj][3]);
      const int byo = (l15*128 + (fj*16 + l4*4)*2) ^ ((l15 & 7) << 4);
      *(short4v*)(PsB + byo) = c;
    }

    #pragma unroll
    for (int kc = 0; kc < 2; ++kc) {
      const int pb = (l15*128 + (kc*32 + l4*8)*2) ^ ((l15 & 7) << 4);
      short8 pa = *(const short8*)(PsB + pb);
      #pragma unroll
      for (int fj = 0; fj < 4; ++fj) {
        const int row = fj*16 + l15;
        short8 vf = *(const short8*)(VsB + ((row*128 + (kc*32 + l4*8)*2) ^ ((row & 7) << 4)));
        o[fj] = __builtin_amdgcn_mfma_f32_16x16x32_bf16(pa, vf, o[fj], 0, 0, 0);
      }
    }
  };

  constexpr int NT = SEQ/64;
  stage(0, 0);
  stage(1, 1);
  int cur = 0, nxt = 2;
  for (int kt = 0; kt < NT-1; ++kt) {
    asm volatile("s_waitcnt vmcnt(2)" ::: "memory");
    __builtin_amdgcn_s_barrier();
    __builtin_amdgcn_sched_barrier(0);
    if (kt + 2 < NT) stage(nxt, kt + 2);
    compute(cur);
    cur = inc3(cur); nxt = inc3(nxt);
  }
  asm volatile("s_waitcnt vmcnt(0)" ::: "memory");
  __builtin_amdgcn_s_barrier();
  __builtin_amdgcn_sched_barrier(0);
  compute(cur);

  const float inv = 1.0f / l;
  float ivr[4];
  #pragma unroll
  for (int r = 0; r < 4; ++r) ivr[r] = __shfl(inv, l4*4 + r, 64);
  #pragma unroll
  for (int fj = 0; fj < 4; ++fj)
    #pragma unroll
    for (int r = 0; r < 4; ++r) {
      const int n = q0 + w*16 + l4*4 + r;
      const int d = fj*16 + l15;
      AO[(((size_t)(b*NH + h)*SEQ + n) << 6) + d] = bf16s(o[fj][r] * ivr[r]);
    }
}

extern "C" void kernel_launch(void* const* d_in, const int* in_sizes, int n_in,
                              void* d_out, int out_size, void* d_ws, size_t ws_size,
                              hipStream_t stream)
{
  const float* query = (const float*)d_in[0];
  const float* key_  = (const float*)d_in[1];
  const float* value = (const float*)d_in[2];
  const float* Wq = (const float*)d_in[3];
  const float* Wk = (const float*)d_in[4];
  const float* Wv = (const float*)d_in[5];
  const float* Wo = (const float*)d_in[6];
  const float* bo = (const float*)d_in[7];

  // 32 MiB ws + d_out-as-scratch choreography:
  // R0[0,8M):  Qb -> Kb -> Vp          R1[8,16M): Qp -> Ao (attn self-overwrite)
  // R2[16,24M): Kp                     R3[24,32M): Wqb,Wkb,Wvb,Wob
  // d_out[16MB]: Vb (staged bf16 value) -> final f32 output
  char* wsb = (char*)d_ws;
  short* Sb  = (short*)(wsb);
  short* Qp  = (short*)(wsb + (8u  << 20));
  short* Kp  = (short*)(wsb + (16u << 20));
  short* Wqb = (short*)(wsb + (24u << 20));
  short* Wkb = (short*)(wsb + (26u << 20));
  short* Wvb = (short*)(wsb + (28u << 20));
  short* Wob = (short*)(wsb + (30u << 20));
  short* Vb  = (short*)d_out;
  short* Vp  = Sb;
  short* Ao  = Qp;

  const int nW = D_MODEL*D_MODEL/8;
  const int nI = 4096*D_MODEL/8;
  castk<<<nW/256, 256, 0, stream>>>(Wq, Wqb, nW, SCALE_LOG2E);
  castk<<<nW/256, 256, 0, stream>>>(Wk, Wkb, nW, 1.f);
  castk<<<nW/256, 256, 0, stream>>>(Wv, Wvb, nW, 1.f);
  castk<<<nW/256, 256, 0, stream>>>(Wo, Wob, nW, 1.f);

  castk<<<nI/256, 256, 0, stream>>>(query, Sb, nI, 1.f);
  gemm_bf<0><<<256, 256, 0, stream>>>(Sb, Wqb, nullptr, Qp);
  castk<<<nI/256, 256, 0, stream>>>(key_, Sb, nI, 1.f);
  gemm_bf<0><<<256, 256, 0, stream>>>(Sb, Wkb, nullptr, Kp);
  castk<<<nI/256, 256, 0, stream>>>(value, Vb, nI, 1.f);
  gemm_bf<1><<<256, 256, 0, stream>>>(Vb, Wvb, nullptr, Vp);

  attn_fwd<<<512, 512, 0, stream>>>(Qp, Kp, Vp, Ao);

  gemm_bf<2><<<256, 256, 0, stream>>>(Ao, Wob, bo, d_out);
}